// Round 5
// baseline (1915.047 us; speedup 1.0000x reference)
//
#include <hip/hip_runtime.h>

// ---------------- small helper kernels ----------------

static __global__ void k_fill(float* __restrict__ p, float v, int n) {
  int i = blockIdx.x * blockDim.x + threadIdx.x;
  if (i < n) p[i] = v;
}

static __global__ void k_deg(float* __restrict__ deg, const int* __restrict__ dst, int E) {
  int e = blockIdx.x * blockDim.x + threadIdx.x;
  if (e < E) atomicAdd(&deg[dst[e]], 1.0f);
}

static __global__ void k_count(float* __restrict__ cnt, const int* __restrict__ batch, int n) {
  int i = blockIdx.x * blockDim.x + threadIdx.x;
  if (i < n) atomicAdd(&cnt[batch[i]], 1.0f);
}

// ---------------- CSR build (indegree scan + position fill) ----------------

static __global__ void k_scan1(const float* __restrict__ degf, int* __restrict__ ex,
                               int* __restrict__ bsum, int n) {
  __shared__ int sm[256];
  int i = blockIdx.x * 256 + threadIdx.x;
  int v = (i < n) ? ((int)degf[i] - 1) : 0;
  sm[threadIdx.x] = v;
  __syncthreads();
  for (int off = 1; off < 256; off <<= 1) {
    int t = (threadIdx.x >= (unsigned)off) ? sm[threadIdx.x - off] : 0;
    __syncthreads();
    sm[threadIdx.x] += t;
    __syncthreads();
  }
  if (i < n) ex[i] = sm[threadIdx.x] - v;
  if (threadIdx.x == 255) bsum[blockIdx.x] = sm[255];
}

static __global__ void k_scan2(int* __restrict__ bsum, int nb) {
  __shared__ int sm[1024];
  __shared__ int carry;
  if (threadIdx.x == 0) carry = 0;
  __syncthreads();
  for (int base = 0; base < nb; base += 1024) {
    int i = base + threadIdx.x;
    int v = (i < nb) ? bsum[i] : 0;
    sm[threadIdx.x] = v;
    __syncthreads();
    for (int off = 1; off < 1024; off <<= 1) {
      int t = (threadIdx.x >= (unsigned)off) ? sm[threadIdx.x - off] : 0;
      __syncthreads();
      sm[threadIdx.x] += t;
      __syncthreads();
    }
    if (i < nb) bsum[i] = sm[threadIdx.x] + carry;
    __syncthreads();
    if (threadIdx.x == 0) carry += sm[1023];
    __syncthreads();
  }
}

// rowptr + fill-cursor + fused dinv = rsqrt(degf)
static __global__ void k_scan3(int* __restrict__ rowptr, int* __restrict__ cursor_ex,
                               const int* __restrict__ bsum, float* __restrict__ dinv,
                               int n, int E) {
  int i = blockIdx.x * 256 + threadIdx.x;
  if (i > n) return;
  if (i == n) { rowptr[n] = E; return; }
  int add = blockIdx.x ? bsum[blockIdx.x - 1] : 0;
  int r = cursor_ex[i] + add;
  rowptr[i] = r;
  cursor_ex[i] = r;
  dinv[i] = 1.0f / sqrtf(dinv[i]);
}

static __global__ void k_fill_csr(const int* __restrict__ src, const int* __restrict__ dst,
                                  int* __restrict__ cursor, int* __restrict__ esrc, int E) {
  int e = blockIdx.x * 256 + threadIdx.x;
  if (e >= E) return;
  int pos = atomicAdd(&cursor[dst[e]], 1);
  esrc[pos] = src[e];
}

// ---------------- pull aggregation (fused self term, no atomics) ----------------
static __global__ void __launch_bounds__(256)
k_agg(float* __restrict__ AG, const float* __restrict__ X,
      const int* __restrict__ rowptr, const int* __restrict__ esrc,
      const float* __restrict__ dinv, int n, int K) {
  int wid = (blockIdx.x * blockDim.x + threadIdx.x) >> 6;
  int lane = threadIdx.x & 63;
  if (wid >= n) return;
  int rs = rowptr[wid], re = rowptr[wid + 1];
  float dv = dinv[wid];
  const float* xr = X + (size_t)wid * K;
  float a0 = (lane < K) ? xr[lane] * dv * dv : 0.0f;
  float a1 = (64 + lane < K) ? xr[64 + lane] * dv * dv : 0.0f;
  for (int e = rs; e < re; ++e) {
    int s = esrc[e];
    float w = dinv[s] * dv;
    const float* xs = X + (size_t)s * K;
    if (lane < K) a0 = fmaf(xs[lane], w, a0);
    if (64 + lane < K) a1 = fmaf(xs[64 + lane], w, a1);
  }
  float* ar = AG + (size_t)wid * K;
  if (lane < K) ar[lane] = a0;
  if (64 + lane < K) ar[64 + lane] = a1;
}

// ---------------- 64x64 tiled GEMM (4x4/thread) for small/ragged shapes ----------------
template<bool RELU>
static __global__ void __launch_bounds__(256)
k_gemm_t(const float* __restrict__ A, const float* __restrict__ W,
         const float* __restrict__ bias, float* __restrict__ Y,
         int n, int Kin, int Kout, int ystride) {
  __shared__ float As[32][68];
  __shared__ float Ws[32][68];

  const int tid = threadIdx.x;
  const int tx = tid & 15, ty = tid >> 4;
  const int r0 = blockIdx.x * 64;
  const int c0 = blockIdx.y * 64;

  float acc[4][4] = {};

  // staging maps: consecutive lanes -> consecutive LDS rows (2-way max conflicts)
  const int ar = tid & 63;          // A: row in tile
  const int akg = (tid >> 6) * 8;   // A: k-group base
  const int wkk = tid & 31;         // W: k row
  const int wcg = (tid >> 5) * 8;   // W: col group base

  const int nch = (Kin + 31) / 32;
  for (int ch = 0; ch < nch; ++ch) {
    const int k0 = ch * 32;
    {
      int grow = r0 + ar;
      bool rok = grow < n;
      const float* arow = A + (size_t)grow * Kin;
#pragma unroll
      for (int i = 0; i < 8; ++i) {
        int k = k0 + akg + i;
        As[akg + i][ar] = (rok && k < Kin) ? arow[k] : 0.0f;
      }
    }
    {
      int gk = k0 + wkk;
      float4 v0 = make_float4(0.f,0.f,0.f,0.f), v1 = v0;
      if (gk < Kin) {
        const float* wp = W + (size_t)gk * Kout + c0 + wcg;
        v0 = *(const float4*)wp;
        v1 = *(const float4*)(wp + 4);
      }
      *(float4*)&Ws[wkk][wcg] = v0;
      *(float4*)&Ws[wkk][wcg + 4] = v1;
    }
    __syncthreads();
#pragma unroll
    for (int k = 0; k < 32; ++k) {
      float4 a4 = *(const float4*)&As[k][ty * 4];
      float4 w4 = *(const float4*)&Ws[k][tx * 4];
      float av[4] = {a4.x, a4.y, a4.z, a4.w};
      float wv[4] = {w4.x, w4.y, w4.z, w4.w};
#pragma unroll
      for (int i = 0; i < 4; ++i)
#pragma unroll
        for (int j = 0; j < 4; ++j)
          acc[i][j] = fmaf(av[i], wv[j], acc[i][j]);
    }
    __syncthreads();
  }

  float4 bv = *(const float4*)&bias[c0 + tx * 4];
  float bb[4] = {bv.x, bv.y, bv.z, bv.w};
#pragma unroll
  for (int i = 0; i < 4; ++i) {
#pragma unroll
    for (int j = 0; j < 4; ++j) {
      acc[i][j] += bb[j];
      if (RELU) acc[i][j] = fmaxf(acc[i][j], 0.0f);
    }
  }
#pragma unroll
  for (int i = 0; i < 4; ++i) {
    int row = r0 + ty * 4 + i;
    if (row < n)
      *(float4*)&Y[(size_t)row * ystride + c0 + tx * 4] =
          make_float4(acc[i][0], acc[i][1], acc[i][2], acc[i][3]);
  }
}

// ---------------- 128x128 tiled GEMM (8x8/thread), K%16==0 ----------------
// rows/cols per thread split as {g*4..g*4+3} and {64+g*4..}, K-chunk 16.
// POOL: segment-sum sorted-batch rows, atomicAdd partials into pooled.
template<bool RELU, bool POOL>
static __global__ void __launch_bounds__(256)
k_gemm128(const float* __restrict__ A, const float* __restrict__ W,
          const float* __restrict__ bias, float* __restrict__ Y,
          int n, int Kin, int Kout,
          const int* __restrict__ batch, int ystride, int colbase) {
  __shared__ float As[16][132];
  __shared__ float Ws[16][132];
  __shared__ float red[POOL ? 64 * 132 : 4];

  const int tid = threadIdx.x;
  const int tx = tid & 15, ty = tid >> 4;
  const int r0 = blockIdx.x * 128;
  const int c0 = blockIdx.y * 128;

  float acc[8][8] = {};

  const int sr = tid >> 1;          // A staging: row 0..127
  const int sk = (tid & 1) * 8;     // A staging: k offset 0/8
  const int wr = tid >> 5;          // W staging: k row 0..7 (+8)
  const int wc = (tid & 31) * 4;    // W staging: col

  const int nch = Kin / 16;
  for (int ch = 0; ch < nch; ++ch) {
    const int k0 = ch * 16;
    {
      int grow = r0 + sr;
      float4 v0 = make_float4(0.f,0.f,0.f,0.f), v1 = v0;
      if (grow < n) {
        const float* ap = A + (size_t)grow * Kin + k0 + sk;
        v0 = *(const float4*)ap;
        v1 = *(const float4*)(ap + 4);
      }
      As[sk + 0][sr] = v0.x; As[sk + 1][sr] = v0.y;
      As[sk + 2][sr] = v0.z; As[sk + 3][sr] = v0.w;
      As[sk + 4][sr] = v1.x; As[sk + 5][sr] = v1.y;
      As[sk + 6][sr] = v1.z; As[sk + 7][sr] = v1.w;
    }
    {
      const float* wp = W + (size_t)(k0 + wr) * Kout + c0 + wc;
      *(float4*)&Ws[wr][wc] = *(const float4*)wp;
      *(float4*)&Ws[wr + 8][wc] = *(const float4*)(wp + (size_t)8 * Kout);
    }
    __syncthreads();
#pragma unroll
    for (int k = 0; k < 16; ++k) {
      float4 a0 = *(const float4*)&As[k][ty * 4];
      float4 a1 = *(const float4*)&As[k][64 + ty * 4];
      float4 w0 = *(const float4*)&Ws[k][tx * 4];
      float4 w1 = *(const float4*)&Ws[k][64 + tx * 4];
      float av[8] = {a0.x,a0.y,a0.z,a0.w,a1.x,a1.y,a1.z,a1.w};
      float wv[8] = {w0.x,w0.y,w0.z,w0.w,w1.x,w1.y,w1.z,w1.w};
#pragma unroll
      for (int i = 0; i < 8; ++i)
#pragma unroll
        for (int j = 0; j < 8; ++j)
          acc[i][j] = fmaf(av[i], wv[j], acc[i][j]);
    }
    __syncthreads();
  }

  float4 b0 = *(const float4*)&bias[c0 + tx * 4];
  float4 b1 = *(const float4*)&bias[c0 + 64 + tx * 4];
  float bb[8] = {b0.x,b0.y,b0.z,b0.w,b1.x,b1.y,b1.z,b1.w};
#pragma unroll
  for (int i = 0; i < 8; ++i) {
#pragma unroll
    for (int j = 0; j < 8; ++j) {
      acc[i][j] += bb[j];
      if (RELU) acc[i][j] = fmaxf(acc[i][j], 0.0f);
    }
  }

  if (!POOL) {
#pragma unroll
    for (int i = 0; i < 8; ++i) {
      int row = r0 + ((i < 4) ? (ty * 4 + i) : (64 + ty * 4 + i - 4));
      if (row < n) {
        float* yp = Y + (size_t)row * ystride + c0;
        *(float4*)&yp[tx * 4] = make_float4(acc[i][0], acc[i][1], acc[i][2], acc[i][3]);
        *(float4*)&yp[64 + tx * 4] = make_float4(acc[i][4], acc[i][5], acc[i][6], acc[i][7]);
      }
    }
  } else {
#pragma unroll
    for (int h = 0; h < 2; ++h) {
      __syncthreads();
#pragma unroll
      for (int i = 0; i < 4; ++i) {
        int ai = h * 4 + i;
        float* rp = &red[(ty * 4 + i) * 132];
        *(float4*)&rp[tx * 4] = make_float4(acc[ai][0], acc[ai][1], acc[ai][2], acc[ai][3]);
        *(float4*)&rp[64 + tx * 4] = make_float4(acc[ai][4], acc[ai][5], acc[ai][6], acc[ai][7]);
      }
      __syncthreads();
      int c = tid & 127;
      int q = tid >> 7;               // two 32-row walkers
      int rb = r0 + h * 64 + q * 32;
      float s = 0.0f;
      int cur = -1;
      for (int rr = 0; rr < 32; ++rr) {
        int row = rb + rr;
        if (row >= n) break;
        int b = batch[row];
        if (b != cur) {
          if (cur >= 0 && s != 0.0f)
            atomicAdd(&Y[(size_t)cur * ystride + colbase + c0 + c], s);
          cur = b; s = 0.0f;
        }
        s += red[(q * 32 + rr) * 132 + c];
      }
      if (cur >= 0 && s != 0.0f)
        atomicAdd(&Y[(size_t)cur * ystride + colbase + c0 + c], s);
    }
  }
}

// pooled[b, colbase+c] /= max(cnt[b],1)
static __global__ void k_pool_div(float* __restrict__ pooled, const float* __restrict__ cnt,
                                  int colbase) {
  int i = blockIdx.x * blockDim.x + threadIdx.x;
  if (i >= 512 * 256) return;
  int b = i >> 8;
  int c = i & 255;
  pooled[b * 512 + colbase + c] /= fmaxf(cnt[b], 1.0f);
}

// out[row] = X[row,:512] . w + b   -- one wave per row
static __global__ void k_out(float* __restrict__ out, const float* __restrict__ X,
                             const float* __restrict__ w, const float* __restrict__ b) {
  int row = blockIdx.x;
  int lane = threadIdx.x;
  float acc = 0.f;
  for (int k = lane; k < 512; k += 64)
    acc = fmaf(X[row * 512 + k], w[k], acc);
#pragma unroll
  for (int off = 32; off; off >>= 1) acc += __shfl_down(acc, off);
  if (lane == 0) out[row] = acc + b[0];
}

// ---------------- launch ----------------

extern "C" void kernel_launch(void* const* d_in, const int* in_sizes, int n_in,
                              void* d_out, int out_size, void* d_ws, size_t ws_size,
                              hipStream_t stream) {
  const float* p_x  = (const float*)d_in[0];
  const int*   p_ei = (const int*)d_in[1];
  const int*   p_bt = (const int*)d_in[2];
  const float* l_x  = (const float*)d_in[3];
  const int*   l_ei = (const int*)d_in[4];
  const int*   l_bt = (const int*)d_in[5];
  const float* pW1 = (const float*)d_in[6],  *pb1 = (const float*)d_in[7];
  const float* pW2 = (const float*)d_in[8],  *pb2 = (const float*)d_in[9];
  const float* pW3 = (const float*)d_in[10], *pb3 = (const float*)d_in[11];
  const float* lW1 = (const float*)d_in[12], *lb1 = (const float*)d_in[13];
  const float* lW2 = (const float*)d_in[14], *lb2 = (const float*)d_in[15];
  const float* lW3 = (const float*)d_in[16], *lb3 = (const float*)d_in[17];
  const float* fc1W = (const float*)d_in[18], *fc1b = (const float*)d_in[19];
  const float* fc2W = (const float*)d_in[20], *fc2b = (const float*)d_in[21];
  const float* oW  = (const float*)d_in[22], *ob  = (const float*)d_in[23];

  const int n_p = in_sizes[2], n_l = in_sizes[5];
  const int E_p = in_sizes[1] / 2, E_l = in_sizes[4] / 2;
  const int IN_P = in_sizes[0] / n_p, IN_L = in_sizes[3] / n_l;   // 41, 78

  char* wsc = (char*)d_ws;
  size_t off = 0;
  auto alloc = [&](size_t bytes) -> void* {
    void* p = wsc + off;
    off = (off + bytes + 255) & ~(size_t)255;
    return p;
  };
  float* dinv_p = (float*)alloc((size_t)n_p * 4);   // degf then rsqrt'd in scan3
  float* dinv_l = (float*)alloc((size_t)n_l * 4);
  float* cnt_p  = (float*)alloc(512 * 4);
  float* cnt_l  = (float*)alloc(512 * 4);
  float* pooled = (float*)alloc(512 * 512 * 4);
  float* F      = (float*)alloc((size_t)n_p * 128 * 4);
  float* AG     = (float*)alloc((size_t)n_p * 128 * 4);
  int* bsum     = (int*)alloc(1024 * 4);
  int* cur_p    = (int*)alloc((size_t)n_p * 4);
  int* row_p    = (int*)alloc(((size_t)n_p + 1) * 4);
  int* esrc_p   = (int*)alloc((size_t)E_p * 4);
  int* cur_l    = (int*)alloc((size_t)n_l * 4);
  int* row_l    = (int*)alloc(((size_t)n_l + 1) * 4);
  int* esrc_l   = (int*)alloc((size_t)E_l * 4);
  float* fc1o   = F;                 // branches done before the FC stack
  float* fc2o   = F + 512 * 1024;
  (void)ws_size; (void)n_in; (void)out_size;

  hipMemsetAsync(pooled, 0, 512 * 512 * 4, stream);
  hipMemsetAsync(cnt_p, 0, 512 * 4, stream);
  hipMemsetAsync(cnt_l, 0, 512 * 4, stream);

  auto gemm64 = [&](const float* A, const float* W, const float* b, float* Y,
                    int n, int Kin, int Kout, int ystride) {
    dim3 g((n + 63) / 64, Kout / 64);
    k_gemm_t<true><<<g, 256, 0, stream>>>(A, W, b, Y, n, Kin, Kout, ystride);
  };
  auto gemm128 = [&](bool pool, const float* A, const float* W, const float* b, float* Y,
                     int n, int Kin, int Kout, const int* batch, int ystride, int colbase) {
    dim3 g((n + 127) / 128, Kout / 128);
    if (pool)
      k_gemm128<true, true><<<g, 256, 0, stream>>>(A, W, b, Y, n, Kin, Kout, batch, ystride, colbase);
    else
      k_gemm128<true, false><<<g, 256, 0, stream>>>(A, W, b, Y, n, Kin, Kout, nullptr, ystride, 0);
  };

  auto branch = [&](const float* x0, const int* ei, const int* batch, int n, int E, int IN,
                    const float* W1, const float* b1, const float* W2, const float* b2,
                    const float* W3, const float* b3, float* dinv, float* cnt,
                    int* cursor, int* rowptr, int* esrc, int colbase) {
    const int* src = ei;
    const int* dst = ei + E;
    const int nb = (n + 255) / 256;
    k_fill<<<nb, 256, 0, stream>>>(dinv, 1.0f, n);
    k_deg<<<(E + 255) / 256, 256, 0, stream>>>(dinv, dst, E);
    k_count<<<nb, 256, 0, stream>>>(cnt, batch, n);
    k_scan1<<<nb, 256, 0, stream>>>(dinv, cursor, bsum, n);
    k_scan2<<<1, 1024, 0, stream>>>(bsum, nb);
    k_scan3<<<(n + 256) / 256 + 1, 256, 0, stream>>>(rowptr, cursor, bsum, dinv, n, E);
    k_fill_csr<<<(E + 255) / 256, 256, 0, stream>>>(src, dst, cursor, esrc, E);
    // layer 1 (ragged Kin 41/78) -> 64-tile
    int gw = (n * 64 + 255) / 256;
    k_agg<<<gw, 256, 0, stream>>>(AG, x0, rowptr, esrc, dinv, n, IN);
    gemm64(AG, W1, b1, F, n, IN, 64, 64);
    // layer 2 -> 128-tile
    k_agg<<<gw, 256, 0, stream>>>(AG, F, rowptr, esrc, dinv, n, 64);
    gemm128(false, AG, W2, b2, F, n, 64, 128, nullptr, 128, 0);
    // layer 3 -> 128-tile + fused mean-pool numerator
    k_agg<<<gw, 256, 0, stream>>>(AG, F, rowptr, esrc, dinv, n, 128);
    gemm128(true, AG, W3, b3, pooled, n, 128, 256, batch, 512, colbase);
  };

  branch(p_x, p_ei, p_bt, n_p, E_p, IN_P, pW1, pb1, pW2, pb2, pW3, pb3,
         dinv_p, cnt_p, cur_p, row_p, esrc_p, 0);
  branch(l_x, l_ei, l_bt, n_l, E_l, IN_L, lW1, lb1, lW2, lb2, lW3, lb3,
         dinv_l, cnt_l, cur_l, row_l, esrc_l, 256);

  k_pool_div<<<(512 * 256 + 255) / 256, 256, 0, stream>>>(pooled, cnt_p, 0);
  k_pool_div<<<(512 * 256 + 255) / 256, 256, 0, stream>>>(pooled, cnt_l, 256);

  // FC stack (n=512 -> 64-tile keeps 128/64 blocks in flight)
  gemm64(pooled, fc1W, fc1b, fc1o, 512, 512, 1024, 1024);
  gemm64(fc1o, fc2W, fc2b, fc2o, 512, 1024, 512, 512);
  k_out<<<512, 64, 0, stream>>>((float*)d_out, fc2o, oW, ob);
}

// Round 7
// 1834.378 us; speedup vs baseline: 1.0440x; 1.0440x over previous
//
#include <hip/hip_runtime.h>

typedef __attribute__((ext_vector_type(8))) short short8;
typedef __attribute__((ext_vector_type(16))) float f32x16;

// ---------------- bf16 split helpers ----------------

__device__ __forceinline__ unsigned short f2bf_rne(float f) {
  unsigned u = __float_as_uint(f);
  u += 0x7fffu + ((u >> 16) & 1u);
  return (unsigned short)(u >> 16);
}
__device__ __forceinline__ float bf2f(unsigned short h) {
  return __uint_as_float(((unsigned)h) << 16);
}

// ---------------- small helper kernels ----------------

static __global__ void k_fill(float* __restrict__ p, float v, int n) {
  int i = blockIdx.x * blockDim.x + threadIdx.x;
  if (i < n) p[i] = v;
}

static __global__ void k_deg(float* __restrict__ deg, const int* __restrict__ dst, int E) {
  int e = blockIdx.x * blockDim.x + threadIdx.x;
  if (e < E) atomicAdd(&deg[dst[e]], 1.0f);
}

static __global__ void k_count(float* __restrict__ cnt, const int* __restrict__ batch, int n) {
  int i = blockIdx.x * blockDim.x + threadIdx.x;
  if (i < n) atomicAdd(&cnt[batch[i]], 1.0f);
}

// ---------------- CSR build ----------------

static __global__ void k_scan1(const float* __restrict__ degf, int* __restrict__ ex,
                               int* __restrict__ bsum, int n) {
  __shared__ int sm[256];
  int i = blockIdx.x * 256 + threadIdx.x;
  int v = (i < n) ? ((int)degf[i] - 1) : 0;
  sm[threadIdx.x] = v;
  __syncthreads();
  for (int off = 1; off < 256; off <<= 1) {
    int t = (threadIdx.x >= (unsigned)off) ? sm[threadIdx.x - off] : 0;
    __syncthreads();
    sm[threadIdx.x] += t;
    __syncthreads();
  }
  if (i < n) ex[i] = sm[threadIdx.x] - v;
  if (threadIdx.x == 255) bsum[blockIdx.x] = sm[255];
}

static __global__ void k_scan2(int* __restrict__ bsum, int nb) {
  __shared__ int sm[1024];
  __shared__ int carry;
  if (threadIdx.x == 0) carry = 0;
  __syncthreads();
  for (int base = 0; base < nb; base += 1024) {
    int i = base + threadIdx.x;
    int v = (i < nb) ? bsum[i] : 0;
    sm[threadIdx.x] = v;
    __syncthreads();
    for (int off = 1; off < 1024; off <<= 1) {
      int t = (threadIdx.x >= (unsigned)off) ? sm[threadIdx.x - off] : 0;
      __syncthreads();
      sm[threadIdx.x] += t;
      __syncthreads();
    }
    if (i < nb) bsum[i] = sm[threadIdx.x] + carry;
    __syncthreads();
    if (threadIdx.x == 0) carry += sm[1023];
    __syncthreads();
  }
}

static __global__ void k_scan3(int* __restrict__ rowptr, int* __restrict__ cursor_ex,
                               const int* __restrict__ bsum, float* __restrict__ dinv,
                               int n, int E) {
  int i = blockIdx.x * 256 + threadIdx.x;
  if (i > n) return;
  if (i == n) { rowptr[n] = E; return; }
  int add = blockIdx.x ? bsum[blockIdx.x - 1] : 0;
  int r = cursor_ex[i] + add;
  rowptr[i] = r;
  cursor_ex[i] = r;
  dinv[i] = 1.0f / sqrtf(dinv[i]);
}

static __global__ void k_fill_csr(const int* __restrict__ src, const int* __restrict__ dst,
                                  int* __restrict__ cursor, int* __restrict__ esrc, int E) {
  int e = blockIdx.x * 256 + threadIdx.x;
  if (e >= E) return;
  int pos = atomicAdd(&cursor[dst[e]], 1);
  esrc[pos] = src[e];
}

// ---------------- pull aggregation ----------------
// SPLIT=false: write f32 AG.  SPLIT=true: write bf16 hi/lo arrays.
template<bool SPLIT>
static __global__ void __launch_bounds__(256)
k_agg(float* __restrict__ AG, unsigned short* __restrict__ AGh, unsigned short* __restrict__ AGl,
      const float* __restrict__ X,
      const int* __restrict__ rowptr, const int* __restrict__ esrc,
      const float* __restrict__ dinv, int n, int K) {
  int wid = (blockIdx.x * blockDim.x + threadIdx.x) >> 6;
  int lane = threadIdx.x & 63;
  if (wid >= n) return;
  int rs = rowptr[wid], re = rowptr[wid + 1];
  float dv = dinv[wid];
  const float* xr = X + (size_t)wid * K;
  float a0 = (lane < K) ? xr[lane] * dv * dv : 0.0f;
  float a1 = (64 + lane < K) ? xr[64 + lane] * dv * dv : 0.0f;
  for (int e = rs; e < re; ++e) {
    int s = esrc[e];
    float w = dinv[s] * dv;
    const float* xs = X + (size_t)s * K;
    if (lane < K) a0 = fmaf(xs[lane], w, a0);
    if (64 + lane < K) a1 = fmaf(xs[64 + lane], w, a1);
  }
  if (!SPLIT) {
    float* ar = AG + (size_t)wid * K;
    if (lane < K) ar[lane] = a0;
    if (64 + lane < K) ar[64 + lane] = a1;
  } else {
    size_t base = (size_t)wid * K;
    if (lane < K) {
      unsigned short h = f2bf_rne(a0);
      AGh[base + lane] = h;
      AGl[base + lane] = f2bf_rne(a0 - bf2f(h));
    }
    if (64 + lane < K) {
      unsigned short h = f2bf_rne(a1);
      AGh[base + 64 + lane] = h;
      AGl[base + 64 + lane] = f2bf_rne(a1 - bf2f(h));
    }
  }
}

// ---------------- W pre-split + transpose:  Wt[c][k] = split(W[k][c]) ----------------
static __global__ void k_wsplit(const float* __restrict__ W,
                                unsigned short* __restrict__ Wth, unsigned short* __restrict__ Wtl,
                                int Kin, int Kout) {
  int idx = blockIdx.x * blockDim.x + threadIdx.x;
  if (idx >= Kin * Kout) return;
  int k = idx / Kout, c = idx - k * Kout;
  float v = W[idx];
  unsigned short h = f2bf_rne(v);
  Wth[(size_t)c * Kin + k] = h;
  Wtl[(size_t)c * Kin + k] = f2bf_rne(v - bf2f(h));
}

// ---------------- split-bf16 MFMA GEMM ----------------
// Y = relu(A @ W + b) with A ~ Ah+Al (bf16), W given transposed-split Bth/Btl [Kout][K].
// Block 128x128, 4 waves (2x2), wave tile 64x64 = 2x2 frags of mfma_f32_32x32x16_bf16.
// 3-term split product: Ah*Bh + Ah*Bl + Al*Bh.
// POOL: segment-sum output rows by sorted batch id into Y[batch*ystride+colbase+col].
template<bool POOL>
static __global__ void __launch_bounds__(256)
k_gemm_mfma(const unsigned short* __restrict__ Ah, const unsigned short* __restrict__ Al,
            const unsigned short* __restrict__ Bth, const unsigned short* __restrict__ Btl,
            const float* __restrict__ bias, float* __restrict__ Y,
            int n, int K, int Kout,
            const int* __restrict__ batch, int ystride, int colbase) {
  __shared__ __align__(16) unsigned short sAh[128 * 32];
  __shared__ __align__(16) unsigned short sAl[128 * 32];
  __shared__ __align__(16) unsigned short sBh[128 * 32];
  __shared__ __align__(16) unsigned short sBl[128 * 32];

  const int tid = threadIdx.x;
  const int lane = tid & 63;
  const int wid = tid >> 6;
  const int wr = wid >> 1, wc = wid & 1;
  const int g = lane >> 5;           // k-half selector within frag
  const int r0 = blockIdx.x * 128;
  const int c0 = blockIdx.y * 128;

  f32x16 acc[2][2] = {};

  const int srow = tid & 127;        // staging row (A) / col (B)
  const int q0 = tid >> 7;           // 0/1

  const int nch = K / 32;
  for (int ch = 0; ch < nch; ++ch) {
    const int k0 = ch * 32;
    if (ch) __syncthreads();
    // stage A (rows) and B (cols) hi/lo, XOR-swizzled [row][k] layout
    {
      bool rok = (r0 + srow) < n;
      size_t abase = (size_t)(r0 + srow) * K + k0;
      size_t bbase = (size_t)(c0 + srow) * K + k0;
      int swz = ((srow >> 1) & 3) << 3;
#pragma unroll
      for (int qq = 0; qq < 2; ++qq) {
        int q = q0 + 2 * qq;
        int sidx = srow * 32 + ((q * 8) ^ swz);
        short8 vh = {}, vl = {};
        if (rok) {
          vh = *(const short8*)&Ah[abase + q * 8];
          vl = *(const short8*)&Al[abase + q * 8];
        }
        *(short8*)&sAh[sidx] = vh;
        *(short8*)&sAl[sidx] = vl;
        *(short8*)&sBh[sidx] = *(const short8*)&Bth[bbase + q * 8];
        *(short8*)&sBl[sidx] = *(const short8*)&Btl[bbase + q * 8];
      }
    }
    __syncthreads();
#pragma unroll
    for (int kk = 0; kk < 2; ++kk) {
      short8 ah[2], al[2], bh[2], bl[2];
#pragma unroll
      for (int f = 0; f < 2; ++f) {
        int ra = wr * 64 + f * 32 + (lane & 31);
        int ka = (kk * 16 + g * 8) ^ (((ra >> 1) & 3) << 3);
        ah[f] = *(const short8*)&sAh[ra * 32 + ka];
        al[f] = *(const short8*)&sAl[ra * 32 + ka];
        int rb = wc * 64 + f * 32 + (lane & 31);
        int kb = (kk * 16 + g * 8) ^ (((rb >> 1) & 3) << 3);
        bh[f] = *(const short8*)&sBh[rb * 32 + kb];
        bl[f] = *(const short8*)&sBl[rb * 32 + kb];
      }
#pragma unroll
      for (int fa = 0; fa < 2; ++fa)
#pragma unroll
        for (int fb = 0; fb < 2; ++fb) {
          acc[fa][fb] = __builtin_amdgcn_mfma_f32_32x32x16_bf16(ah[fa], bh[fb], acc[fa][fb], 0, 0, 0);
          acc[fa][fb] = __builtin_amdgcn_mfma_f32_32x32x16_bf16(ah[fa], bl[fb], acc[fa][fb], 0, 0, 0);
          acc[fa][fb] = __builtin_amdgcn_mfma_f32_32x32x16_bf16(al[fa], bh[fb], acc[fa][fb], 0, 0, 0);
        }
    }
  }

  // epilogue. C/D layout (HW-verified): col = lane&31, row = (reg&3)+8*(reg>>2)+4*(lane>>5)
  if (!POOL) {
#pragma unroll
    for (int fa = 0; fa < 2; ++fa)
#pragma unroll
      for (int fb = 0; fb < 2; ++fb) {
        int col = c0 + wc * 64 + fb * 32 + (lane & 31);
        float bcol = bias[col];
#pragma unroll
        for (int r = 0; r < 16; ++r) {
          int grow = r0 + wr * 64 + fa * 32 + (r & 3) + 8 * (r >> 2) + 4 * g;
          if (grow < n) {
            float v = fmaxf(acc[fa][fb][r] + bcol, 0.0f);
            Y[(size_t)grow * ystride + col] = v;
          }
        }
      }
  } else {
#pragma unroll
    for (int fa = 0; fa < 2; ++fa)
#pragma unroll
      for (int fb = 0; fb < 2; ++fb) {
        int col = colbase + c0 + wc * 64 + fb * 32 + (lane & 31);
        float bcol = bias[c0 + wc * 64 + fb * 32 + (lane & 31)];
        float s = 0.0f;
        int cur = -1;
#pragma unroll
        for (int r = 0; r < 16; ++r) {
          int grow = r0 + wr * 64 + fa * 32 + (r & 3) + 8 * (r >> 2) + 4 * g;
          if (grow < n) {
            int b = batch[grow];
            if (b != cur) {
              if (cur >= 0 && s != 0.0f)
                atomicAdd(&Y[(size_t)cur * ystride + col], s);
              cur = b;
              s = 0.0f;
            }
            s += fmaxf(acc[fa][fb][r] + bcol, 0.0f);
          }
        }
        if (cur >= 0 && s != 0.0f)
          atomicAdd(&Y[(size_t)cur * ystride + col], s);
      }
  }
}

// ---------------- 64x64 tiled f32 GEMM (L1 ragged-K + FC stack) ----------------
template<bool RELU>
static __global__ void __launch_bounds__(256)
k_gemm_t(const float* __restrict__ A, const float* __restrict__ W,
         const float* __restrict__ bias, float* __restrict__ Y,
         int n, int Kin, int Kout, int ystride) {
  __shared__ float As[32][68];
  __shared__ float Ws[32][68];

  const int tid = threadIdx.x;
  const int tx = tid & 15, ty = tid >> 4;
  const int r0 = blockIdx.x * 64;
  const int c0 = blockIdx.y * 64;

  float acc[4][4] = {};

  const int ar = tid & 63;
  const int akg = (tid >> 6) * 8;
  const int wkk = tid & 31;
  const int wcg = (tid >> 5) * 8;

  const int nch = (Kin + 31) / 32;
  for (int ch = 0; ch < nch; ++ch) {
    const int k0 = ch * 32;
    {
      int grow = r0 + ar;
      bool rok = grow < n;
      const float* arow = A + (size_t)grow * Kin;
#pragma unroll
      for (int i = 0; i < 8; ++i) {
        int k = k0 + akg + i;
        As[akg + i][ar] = (rok && k < Kin) ? arow[k] : 0.0f;
      }
    }
    {
      int gk = k0 + wkk;
      float4 v0 = make_float4(0.f, 0.f, 0.f, 0.f), v1 = v0;
      if (gk < Kin) {
        const float* wp = W + (size_t)gk * Kout + c0 + wcg;
        v0 = *(const float4*)wp;
        v1 = *(const float4*)(wp + 4);
      }
      *(float4*)&Ws[wkk][wcg] = v0;
      *(float4*)&Ws[wkk][wcg + 4] = v1;
    }
    __syncthreads();
#pragma unroll
    for (int k = 0; k < 32; ++k) {
      float4 a4 = *(const float4*)&As[k][ty * 4];
      float4 w4 = *(const float4*)&Ws[k][tx * 4];
      float av[4] = {a4.x, a4.y, a4.z, a4.w};
      float wv[4] = {w4.x, w4.y, w4.z, w4.w};
#pragma unroll
      for (int i = 0; i < 4; ++i)
#pragma unroll
        for (int j = 0; j < 4; ++j)
          acc[i][j] = fmaf(av[i], wv[j], acc[i][j]);
    }
    __syncthreads();
  }

  float4 bv = *(const float4*)&bias[c0 + tx * 4];
  float bb[4] = {bv.x, bv.y, bv.z, bv.w};
#pragma unroll
  for (int i = 0; i < 4; ++i) {
    int row = r0 + ty * 4 + i;
    if (row < n) {
      float o[4];
#pragma unroll
      for (int j = 0; j < 4; ++j) {
        o[j] = acc[i][j] + bb[j];
        if (RELU) o[j] = fmaxf(o[j], 0.0f);
      }
      *(float4*)&Y[(size_t)row * ystride + c0 + tx * 4] = make_float4(o[0], o[1], o[2], o[3]);
    }
  }
}

// pooled[b, colbase+c] /= max(cnt[b],1)
static __global__ void k_pool_div(float* __restrict__ pooled, const float* __restrict__ cnt,
                                  int colbase) {
  int i = blockIdx.x * blockDim.x + threadIdx.x;
  if (i >= 512 * 256) return;
  int b = i >> 8;
  int c = i & 255;
  pooled[b * 512 + colbase + c] /= fmaxf(cnt[b], 1.0f);
}

// out[row] = X[row,:512] . w + b
static __global__ void k_out(float* __restrict__ out, const float* __restrict__ X,
                             const float* __restrict__ w, const float* __restrict__ b) {
  int row = blockIdx.x;
  int lane = threadIdx.x;
  float acc = 0.f;
  for (int k = lane; k < 512; k += 64)
    acc = fmaf(X[row * 512 + k], w[k], acc);
#pragma unroll
  for (int off = 32; off; off >>= 1) acc += __shfl_down(acc, off);
  if (lane == 0) out[row] = acc + b[0];
}

// ---------------- launch ----------------

extern "C" void kernel_launch(void* const* d_in, const int* in_sizes, int n_in,
                              void* d_out, int out_size, void* d_ws, size_t ws_size,
                              hipStream_t stream) {
  const float* p_x  = (const float*)d_in[0];
  const int*   p_ei = (const int*)d_in[1];
  const int*   p_bt = (const int*)d_in[2];
  const float* l_x  = (const float*)d_in[3];
  const int*   l_ei = (const int*)d_in[4];
  const int*   l_bt = (const int*)d_in[5];
  const float* pW1 = (const float*)d_in[6],  *pb1 = (const float*)d_in[7];
  const float* pW2 = (const float*)d_in[8],  *pb2 = (const float*)d_in[9];
  const float* pW3 = (const float*)d_in[10], *pb3 = (const float*)d_in[11];
  const float* lW1 = (const float*)d_in[12], *lb1 = (const float*)d_in[13];
  const float* lW2 = (const float*)d_in[14], *lb2 = (const float*)d_in[15];
  const float* lW3 = (const float*)d_in[16], *lb3 = (const float*)d_in[17];
  const float* fc1W = (const float*)d_in[18], *fc1b = (const float*)d_in[19];
  const float* fc2W = (const float*)d_in[20], *fc2b = (const float*)d_in[21];
  const float* oW  = (const float*)d_in[22], *ob  = (const float*)d_in[23];

  const int n_p = in_sizes[2], n_l = in_sizes[5];
  const int E_p = in_sizes[1] / 2, E_l = in_sizes[4] / 2;
  const int IN_P = in_sizes[0] / n_p, IN_L = in_sizes[3] / n_l;   // 41, 78

  char* wsc = (char*)d_ws;
  size_t off = 0;
  auto alloc = [&](size_t bytes) -> void* {
    void* p = wsc + off;
    off = (off + bytes + 255) & ~(size_t)255;
    return p;
  };
  float* dinv_p = (float*)alloc((size_t)n_p * 4);
  float* dinv_l = (float*)alloc((size_t)n_l * 4);
  float* cnt_p  = (float*)alloc(512 * 4);
  float* cnt_l  = (float*)alloc(512 * 4);
  float* pooled = (float*)alloc(512 * 512 * 4);
  float* F      = (float*)alloc((size_t)n_p * 128 * 4);
  // AGh+AGl region (contiguous); AGf (layer-1 f32 AG, K<=78 -> 64 MB) ALIASES it.
  // Legal: AGf is dead after layer-1's GEMM; AGh/AGl first written in layer-2 agg.
  unsigned short* AGh = (unsigned short*)alloc((size_t)n_p * 128 * 2);
  unsigned short* AGl = (unsigned short*)alloc((size_t)n_p * 128 * 2);
  float* AGf    = (float*)AGh;       // spans AGh and part of AGl (64 MB < 102.4 MB)
  unsigned short* W2th = (unsigned short*)alloc(64 * 128 * 2);
  unsigned short* W2tl = (unsigned short*)alloc(64 * 128 * 2);
  unsigned short* W3th = (unsigned short*)alloc(128 * 256 * 2);
  unsigned short* W3tl = (unsigned short*)alloc(128 * 256 * 2);
  int* bsum     = (int*)alloc(1024 * 4);
  int* cur_p    = (int*)alloc((size_t)n_p * 4);
  int* row_p    = (int*)alloc(((size_t)n_p + 1) * 4);
  int* esrc_p   = (int*)alloc((size_t)E_p * 4);
  int* cur_l    = (int*)alloc((size_t)n_l * 4);
  int* row_l    = (int*)alloc(((size_t)n_l + 1) * 4);
  int* esrc_l   = (int*)alloc((size_t)E_l * 4);
  float* fc1o   = F;                 // branches done before the FC stack
  float* fc2o   = F + 512 * 1024;
  (void)ws_size; (void)n_in; (void)out_size;

  hipMemsetAsync(pooled, 0, 512 * 512 * 4, stream);
  hipMemsetAsync(cnt_p, 0, 512 * 4, stream);
  hipMemsetAsync(cnt_l, 0, 512 * 4, stream);

  auto gemm64 = [&](const float* A, const float* W, const float* b, float* Y,
                    int n, int Kin, int Kout, int ystride) {
    dim3 grd((n + 63) / 64, Kout / 64);
    k_gemm_t<true><<<grd, 256, 0, stream>>>(A, W, b, Y, n, Kin, Kout, ystride);
  };

  auto branch = [&](const float* x0, const int* ei, const int* batch, int n, int E, int IN,
                    const float* W1, const float* b1, const float* W2, const float* b2,
                    const float* W3, const float* b3, float* dinv, float* cnt,
                    int* cursor, int* rowptr, int* esrc, int colbase) {
    const int* src = ei;
    const int* dst = ei + E;
    const int nb = (n + 255) / 256;
    k_fill<<<nb, 256, 0, stream>>>(dinv, 1.0f, n);
    k_deg<<<(E + 255) / 256, 256, 0, stream>>>(dinv, dst, E);
    k_count<<<nb, 256, 0, stream>>>(cnt, batch, n);
    k_scan1<<<nb, 256, 0, stream>>>(dinv, cursor, bsum, n);
    k_scan2<<<1, 1024, 0, stream>>>(bsum, nb);
    k_scan3<<<(n + 256) / 256 + 1, 256, 0, stream>>>(rowptr, cursor, bsum, dinv, n, E);
    k_fill_csr<<<(E + 255) / 256, 256, 0, stream>>>(src, dst, cursor, esrc, E);
    // W pre-split
    k_wsplit<<<(64 * 128 + 255) / 256, 256, 0, stream>>>(W2, W2th, W2tl, 64, 128);
    k_wsplit<<<(128 * 256 + 255) / 256, 256, 0, stream>>>(W3, W3th, W3tl, 128, 256);
    int gw = (n * 64 + 255) / 256;
    // layer 1 (ragged Kin) -> f32 64-tile
    k_agg<false><<<gw, 256, 0, stream>>>(AGf, nullptr, nullptr, x0, rowptr, esrc, dinv, n, IN);
    gemm64(AGf, W1, b1, F, n, IN, 64, 64);
    // layer 2: split agg -> MFMA GEMM (K=64 -> 128)
    k_agg<true><<<gw, 256, 0, stream>>>(nullptr, AGh, AGl, F, rowptr, esrc, dinv, n, 64);
    {
      dim3 grd((n + 127) / 128, 1);
      k_gemm_mfma<false><<<grd, 256, 0, stream>>>(AGh, AGl, W2th, W2tl, b2, F,
                                                  n, 64, 128, nullptr, 128, 0);
    }
    // layer 3: split agg -> MFMA GEMM (K=128 -> 256) + fused mean-pool numerator
    k_agg<true><<<gw, 256, 0, stream>>>(nullptr, AGh, AGl, F, rowptr, esrc, dinv, n, 128);
    {
      dim3 grd((n + 127) / 128, 2);
      k_gemm_mfma<true><<<grd, 256, 0, stream>>>(AGh, AGl, W3th, W3tl, b3, pooled,
                                                 n, 128, 256, batch, 512, colbase);
    }
  };

  branch(p_x, p_ei, p_bt, n_p, E_p, IN_P, pW1, pb1, pW2, pb2, pW3, pb3,
         dinv_p, cnt_p, cur_p, row_p, esrc_p, 0);
  branch(l_x, l_ei, l_bt, n_l, E_l, IN_L, lW1, lb1, lW2, lb2, lW3, lb3,
         dinv_l, cnt_l, cur_l, row_l, esrc_l, 256);

  k_pool_div<<<(512 * 256 + 255) / 256, 256, 0, stream>>>(pooled, cnt_p, 0);
  k_pool_div<<<(512 * 256 + 255) / 256, 256, 0, stream>>>(pooled, cnt_l, 256);

  // FC stack (f32 path)
  gemm64(pooled, fc1W, fc1b, fc1o, 512, 512, 1024, 1024);
  gemm64(fc1o, fc2W, fc2b, fc2o, 512, 1024, 512, 512);
  k_out<<<512, 64, 0, stream>>>((float*)d_out, fc2o, oW, ob);
}

// Round 8
// 1562.365 us; speedup vs baseline: 1.2257x; 1.1741x over previous
//
#include <hip/hip_runtime.h>

typedef __attribute__((ext_vector_type(8))) short short8;
typedef __attribute__((ext_vector_type(16))) float f32x16;

// ---------------- bf16 split helpers ----------------

__device__ __forceinline__ unsigned short f2bf_rne(float f) {
  unsigned u = __float_as_uint(f);
  u += 0x7fffu + ((u >> 16) & 1u);
  return (unsigned short)(u >> 16);
}
__device__ __forceinline__ float bf2f(unsigned short h) {
  return __uint_as_float(((unsigned)h) << 16);
}

// ---------------- small helper kernels ----------------

static __global__ void k_fill(float* __restrict__ p, float v, int n) {
  int i = blockIdx.x * blockDim.x + threadIdx.x;
  if (i < n) p[i] = v;
}

static __global__ void k_deg(float* __restrict__ deg, const int* __restrict__ dst, int E) {
  int e = blockIdx.x * blockDim.x + threadIdx.x;
  if (e < E) atomicAdd(&deg[dst[e]], 1.0f);
}

// cnt[b] = run-length of b in SORTED batch (two binary searches, no atomics)
static __global__ void k_count_sorted(float* __restrict__ cnt, const int* __restrict__ batch,
                                      int n, int nb) {
  int b = blockIdx.x * blockDim.x + threadIdx.x;
  if (b >= nb) return;
  int lo = 0, hi = n;
  while (lo < hi) { int mid = (lo + hi) >> 1; if (batch[mid] < b) lo = mid + 1; else hi = mid; }
  int start = lo;
  lo = 0; hi = n;
  while (lo < hi) { int mid = (lo + hi) >> 1; if (batch[mid] < b + 1) lo = mid + 1; else hi = mid; }
  cnt[b] = (float)(lo - start);
}

// ---------------- CSR build ----------------

static __global__ void k_scan1(const float* __restrict__ degf, int* __restrict__ ex,
                               int* __restrict__ bsum, int n) {
  __shared__ int sm[256];
  int i = blockIdx.x * 256 + threadIdx.x;
  int v = (i < n) ? ((int)degf[i] - 1) : 0;
  sm[threadIdx.x] = v;
  __syncthreads();
  for (int off = 1; off < 256; off <<= 1) {
    int t = (threadIdx.x >= (unsigned)off) ? sm[threadIdx.x - off] : 0;
    __syncthreads();
    sm[threadIdx.x] += t;
    __syncthreads();
  }
  if (i < n) ex[i] = sm[threadIdx.x] - v;
  if (threadIdx.x == 255) bsum[blockIdx.x] = sm[255];
}

static __global__ void k_scan2(int* __restrict__ bsum, int nb) {
  __shared__ int sm[1024];
  __shared__ int carry;
  if (threadIdx.x == 0) carry = 0;
  __syncthreads();
  for (int base = 0; base < nb; base += 1024) {
    int i = base + threadIdx.x;
    int v = (i < nb) ? bsum[i] : 0;
    sm[threadIdx.x] = v;
    __syncthreads();
    for (int off = 1; off < 1024; off <<= 1) {
      int t = (threadIdx.x >= (unsigned)off) ? sm[threadIdx.x - off] : 0;
      __syncthreads();
      sm[threadIdx.x] += t;
      __syncthreads();
    }
    if (i < nb) bsum[i] = sm[threadIdx.x] + carry;
    __syncthreads();
    if (threadIdx.x == 0) carry += sm[1023];
    __syncthreads();
  }
}

static __global__ void k_scan3(int* __restrict__ rowptr, int* __restrict__ cursor_ex,
                               const int* __restrict__ bsum, float* __restrict__ dinv,
                               int n, int E) {
  int i = blockIdx.x * 256 + threadIdx.x;
  if (i > n) return;
  if (i == n) { rowptr[n] = E; return; }
  int add = blockIdx.x ? bsum[blockIdx.x - 1] : 0;
  int r = cursor_ex[i] + add;
  rowptr[i] = r;
  cursor_ex[i] = r;
  dinv[i] = 1.0f / sqrtf(dinv[i]);
}

static __global__ void k_fill_csr(const int* __restrict__ src, const int* __restrict__ dst,
                                  int* __restrict__ cursor, int* __restrict__ esrc, int E) {
  int e = blockIdx.x * 256 + threadIdx.x;
  if (e >= E) return;
  int pos = atomicAdd(&cursor[dst[e]], 1);
  esrc[pos] = src[e];
}

// ---------------- pull aggregation ----------------
// SPLIT=false: write f32 AG.  SPLIT=true: write bf16 hi/lo arrays.
template<bool SPLIT>
static __global__ void __launch_bounds__(256)
k_agg(float* __restrict__ AG, unsigned short* __restrict__ AGh, unsigned short* __restrict__ AGl,
      const float* __restrict__ X,
      const int* __restrict__ rowptr, const int* __restrict__ esrc,
      const float* __restrict__ dinv, int n, int K) {
  int wid = (blockIdx.x * blockDim.x + threadIdx.x) >> 6;
  int lane = threadIdx.x & 63;
  if (wid >= n) return;
  int rs = rowptr[wid], re = rowptr[wid + 1];
  float dv = dinv[wid];
  const float* xr = X + (size_t)wid * K;
  float a0 = (lane < K) ? xr[lane] * dv * dv : 0.0f;
  float a1 = (64 + lane < K) ? xr[64 + lane] * dv * dv : 0.0f;
  for (int e = rs; e < re; ++e) {
    int s = esrc[e];
    float w = dinv[s] * dv;
    const float* xs = X + (size_t)s * K;
    if (lane < K) a0 = fmaf(xs[lane], w, a0);
    if (64 + lane < K) a1 = fmaf(xs[64 + lane], w, a1);
  }
  if (!SPLIT) {
    float* ar = AG + (size_t)wid * K;
    if (lane < K) ar[lane] = a0;
    if (64 + lane < K) ar[64 + lane] = a1;
  } else {
    size_t base = (size_t)wid * K;
    if (lane < K) {
      unsigned short h = f2bf_rne(a0);
      AGh[base + lane] = h;
      AGl[base + lane] = f2bf_rne(a0 - bf2f(h));
    }
    if (64 + lane < K) {
      unsigned short h = f2bf_rne(a1);
      AGh[base + 64 + lane] = h;
      AGl[base + 64 + lane] = f2bf_rne(a1 - bf2f(h));
    }
  }
}

// ---------------- W pre-split + transpose:  Wt[c][k] = split(W[k][c]) ----------------
static __global__ void k_wsplit(const float* __restrict__ W,
                                unsigned short* __restrict__ Wth, unsigned short* __restrict__ Wtl,
                                int Kin, int Kout) {
  int idx = blockIdx.x * blockDim.x + threadIdx.x;
  if (idx >= Kin * Kout) return;
  int k = idx / Kout, c = idx - k * Kout;
  float v = W[idx];
  unsigned short h = f2bf_rne(v);
  Wth[(size_t)c * Kin + k] = h;
  Wtl[(size_t)c * Kin + k] = f2bf_rne(v - bf2f(h));
}

// ---------------- split-bf16 MFMA GEMM ----------------
// Y = relu(A @ W + b) with A ~ Ah+Al (bf16), W given transposed-split Bth/Btl [Kout][K].
// Block 128x128, 4 waves (2x2), wave tile 64x64 = 2x2 frags of mfma_f32_32x32x16_bf16.
// 3-term split product: Ah*Bh + Ah*Bl + Al*Bh.
// POOL: segment-sum output rows by sorted batch id into Y[batch*ystride+colbase+col].
template<bool POOL>
static __global__ void __launch_bounds__(256)
k_gemm_mfma(const unsigned short* __restrict__ Ah, const unsigned short* __restrict__ Al,
            const unsigned short* __restrict__ Bth, const unsigned short* __restrict__ Btl,
            const float* __restrict__ bias, float* __restrict__ Y,
            int n, int K, int Kout,
            const int* __restrict__ batch, int ystride, int colbase) {
  __shared__ __align__(16) unsigned short sAh[128 * 32];
  __shared__ __align__(16) unsigned short sAl[128 * 32];
  __shared__ __align__(16) unsigned short sBh[128 * 32];
  __shared__ __align__(16) unsigned short sBl[128 * 32];

  const int tid = threadIdx.x;
  const int lane = tid & 63;
  const int wid = tid >> 6;
  const int wr = wid >> 1, wc = wid & 1;
  const int g = lane >> 5;           // k-half selector within frag
  const int r0 = blockIdx.x * 128;
  const int c0 = blockIdx.y * 128;

  f32x16 acc[2][2] = {};

  const int srow = tid & 127;        // staging row (A) / col (B)
  const int q0 = tid >> 7;           // 0/1

  const int nch = K / 32;
  for (int ch = 0; ch < nch; ++ch) {
    const int k0 = ch * 32;
    if (ch) __syncthreads();
    // stage A (rows) and B (cols) hi/lo, XOR-swizzled [row][k] layout
    {
      bool rok = (r0 + srow) < n;
      size_t abase = (size_t)(r0 + srow) * K + k0;
      size_t bbase = (size_t)(c0 + srow) * K + k0;
      int swz = ((srow >> 1) & 3) << 3;
#pragma unroll
      for (int qq = 0; qq < 2; ++qq) {
        int q = q0 + 2 * qq;
        int sidx = srow * 32 + ((q * 8) ^ swz);
        short8 vh = {}, vl = {};
        if (rok) {
          vh = *(const short8*)&Ah[abase + q * 8];
          vl = *(const short8*)&Al[abase + q * 8];
        }
        *(short8*)&sAh[sidx] = vh;
        *(short8*)&sAl[sidx] = vl;
        *(short8*)&sBh[sidx] = *(const short8*)&Bth[bbase + q * 8];
        *(short8*)&sBl[sidx] = *(const short8*)&Btl[bbase + q * 8];
      }
    }
    __syncthreads();
#pragma unroll
    for (int kk = 0; kk < 2; ++kk) {
      short8 ah[2], al[2], bh[2], bl[2];
#pragma unroll
      for (int f = 0; f < 2; ++f) {
        int ra = wr * 64 + f * 32 + (lane & 31);
        int ka = (kk * 16 + g * 8) ^ (((ra >> 1) & 3) << 3);
        ah[f] = *(const short8*)&sAh[ra * 32 + ka];
        al[f] = *(const short8*)&sAl[ra * 32 + ka];
        int rb = wc * 64 + f * 32 + (lane & 31);
        int kb = (kk * 16 + g * 8) ^ (((rb >> 1) & 3) << 3);
        bh[f] = *(const short8*)&sBh[rb * 32 + kb];
        bl[f] = *(const short8*)&sBl[rb * 32 + kb];
      }
#pragma unroll
      for (int fa = 0; fa < 2; ++fa)
#pragma unroll
        for (int fb = 0; fb < 2; ++fb) {
          acc[fa][fb] = __builtin_amdgcn_mfma_f32_32x32x16_bf16(ah[fa], bh[fb], acc[fa][fb], 0, 0, 0);
          acc[fa][fb] = __builtin_amdgcn_mfma_f32_32x32x16_bf16(ah[fa], bl[fb], acc[fa][fb], 0, 0, 0);
          acc[fa][fb] = __builtin_amdgcn_mfma_f32_32x32x16_bf16(al[fa], bh[fb], acc[fa][fb], 0, 0, 0);
        }
    }
  }

  // epilogue. C/D layout (HW-verified): col = lane&31, row = (reg&3)+8*(reg>>2)+4*(lane>>5)
  if (!POOL) {
#pragma unroll
    for (int fa = 0; fa < 2; ++fa)
#pragma unroll
      for (int fb = 0; fb < 2; ++fb) {
        int col = c0 + wc * 64 + fb * 32 + (lane & 31);
        float bcol = bias[col];
#pragma unroll
        for (int r = 0; r < 16; ++r) {
          int grow = r0 + wr * 64 + fa * 32 + (r & 3) + 8 * (r >> 2) + 4 * g;
          if (grow < n) {
            float v = fmaxf(acc[fa][fb][r] + bcol, 0.0f);
            Y[(size_t)grow * ystride + col] = v;
          }
        }
      }
  } else {
#pragma unroll
    for (int fa = 0; fa < 2; ++fa)
#pragma unroll
      for (int fb = 0; fb < 2; ++fb) {
        int col = colbase + c0 + wc * 64 + fb * 32 + (lane & 31);
        float bcol = bias[c0 + wc * 64 + fb * 32 + (lane & 31)];
        float s = 0.0f;
        int cur = -1;
#pragma unroll
        for (int r = 0; r < 16; ++r) {
          int grow = r0 + wr * 64 + fa * 32 + (r & 3) + 8 * (r >> 2) + 4 * g;
          if (grow < n) {
            int b = batch[grow];
            if (b != cur) {
              if (cur >= 0 && s != 0.0f)
                atomicAdd(&Y[(size_t)cur * ystride + col], s);
              cur = b;
              s = 0.0f;
            }
            s += fmaxf(acc[fa][fb][r] + bcol, 0.0f);
          }
        }
        if (cur >= 0 && s != 0.0f)
          atomicAdd(&Y[(size_t)cur * ystride + col], s);
      }
  }
}

// ---------------- 64x64 tiled f32 GEMM (L1 ragged-K + FC stack) ----------------
template<bool RELU>
static __global__ void __launch_bounds__(256)
k_gemm_t(const float* __restrict__ A, const float* __restrict__ W,
         const float* __restrict__ bias, float* __restrict__ Y,
         int n, int Kin, int Kout, int ystride) {
  __shared__ float As[32][68];
  __shared__ float Ws[32][68];

  const int tid = threadIdx.x;
  const int tx = tid & 15, ty = tid >> 4;
  const int r0 = blockIdx.x * 64;
  const int c0 = blockIdx.y * 64;

  float acc[4][4] = {};

  const int ar = tid & 63;
  const int akg = (tid >> 6) * 8;
  const int wkk = tid & 31;
  const int wcg = (tid >> 5) * 8;

  const int nch = (Kin + 31) / 32;
  for (int ch = 0; ch < nch; ++ch) {
    const int k0 = ch * 32;
    {
      int grow = r0 + ar;
      bool rok = grow < n;
      const float* arow = A + (size_t)grow * Kin;
#pragma unroll
      for (int i = 0; i < 8; ++i) {
        int k = k0 + akg + i;
        As[akg + i][ar] = (rok && k < Kin) ? arow[k] : 0.0f;
      }
    }
    {
      int gk = k0 + wkk;
      float4 v0 = make_float4(0.f, 0.f, 0.f, 0.f), v1 = v0;
      if (gk < Kin) {
        const float* wp = W + (size_t)gk * Kout + c0 + wcg;
        v0 = *(const float4*)wp;
        v1 = *(const float4*)(wp + 4);
      }
      *(float4*)&Ws[wkk][wcg] = v0;
      *(float4*)&Ws[wkk][wcg + 4] = v1;
    }
    __syncthreads();
#pragma unroll
    for (int k = 0; k < 32; ++k) {
      float4 a4 = *(const float4*)&As[k][ty * 4];
      float4 w4 = *(const float4*)&Ws[k][tx * 4];
      float av[4] = {a4.x, a4.y, a4.z, a4.w};
      float wv[4] = {w4.x, w4.y, w4.z, w4.w};
#pragma unroll
      for (int i = 0; i < 4; ++i)
#pragma unroll
        for (int j = 0; j < 4; ++j)
          acc[i][j] = fmaf(av[i], wv[j], acc[i][j]);
    }
    __syncthreads();
  }

  float4 bv = *(const float4*)&bias[c0 + tx * 4];
  float bb[4] = {bv.x, bv.y, bv.z, bv.w};
#pragma unroll
  for (int i = 0; i < 4; ++i) {
    int row = r0 + ty * 4 + i;
    if (row < n) {
      float o[4];
#pragma unroll
      for (int j = 0; j < 4; ++j) {
        o[j] = acc[i][j] + bb[j];
        if (RELU) o[j] = fmaxf(o[j], 0.0f);
      }
      *(float4*)&Y[(size_t)row * ystride + c0 + tx * 4] = make_float4(o[0], o[1], o[2], o[3]);
    }
  }
}

// pooled[b, colbase+c] /= max(cnt[b],1)
static __global__ void k_pool_div(float* __restrict__ pooled, const float* __restrict__ cnt,
                                  int colbase) {
  int i = blockIdx.x * blockDim.x + threadIdx.x;
  if (i >= 512 * 256) return;
  int b = i >> 8;
  int c = i & 255;
  pooled[b * 512 + colbase + c] /= fmaxf(cnt[b], 1.0f);
}

// out[row] = X[row,:512] . w + b
static __global__ void k_out(float* __restrict__ out, const float* __restrict__ X,
                             const float* __restrict__ w, const float* __restrict__ b) {
  int row = blockIdx.x;
  int lane = threadIdx.x;
  float acc = 0.f;
  for (int k = lane; k < 512; k += 64)
    acc = fmaf(X[row * 512 + k], w[k], acc);
#pragma unroll
  for (int off = 32; off; off >>= 1) acc += __shfl_down(acc, off);
  if (lane == 0) out[row] = acc + b[0];
}

// ---------------- launch ----------------

extern "C" void kernel_launch(void* const* d_in, const int* in_sizes, int n_in,
                              void* d_out, int out_size, void* d_ws, size_t ws_size,
                              hipStream_t stream) {
  const float* p_x  = (const float*)d_in[0];
  const int*   p_ei = (const int*)d_in[1];
  const int*   p_bt = (const int*)d_in[2];
  const float* l_x  = (const float*)d_in[3];
  const int*   l_ei = (const int*)d_in[4];
  const int*   l_bt = (const int*)d_in[5];
  const float* pW1 = (const float*)d_in[6],  *pb1 = (const float*)d_in[7];
  const float* pW2 = (const float*)d_in[8],  *pb2 = (const float*)d_in[9];
  const float* pW3 = (const float*)d_in[10], *pb3 = (const float*)d_in[11];
  const float* lW1 = (const float*)d_in[12], *lb1 = (const float*)d_in[13];
  const float* lW2 = (const float*)d_in[14], *lb2 = (const float*)d_in[15];
  const float* lW3 = (const float*)d_in[16], *lb3 = (const float*)d_in[17];
  const float* fc1W = (const float*)d_in[18], *fc1b = (const float*)d_in[19];
  const float* fc2W = (const float*)d_in[20], *fc2b = (const float*)d_in[21];
  const float* oW  = (const float*)d_in[22], *ob  = (const float*)d_in[23];

  const int n_p = in_sizes[2], n_l = in_sizes[5];
  const int E_p = in_sizes[1] / 2, E_l = in_sizes[4] / 2;
  const int IN_P = in_sizes[0] / n_p, IN_L = in_sizes[3] / n_l;   // 41, 78

  char* wsc = (char*)d_ws;
  size_t off = 0;
  auto alloc = [&](size_t bytes) -> void* {
    void* p = wsc + off;
    off = (off + bytes + 255) & ~(size_t)255;
    return p;
  };
  float* dinv_p = (float*)alloc((size_t)n_p * 4);
  float* dinv_l = (float*)alloc((size_t)n_l * 4);
  float* cnt_p  = (float*)alloc(512 * 4);
  float* cnt_l  = (float*)alloc(512 * 4);
  float* pooled = (float*)alloc(512 * 512 * 4);
  float* F      = (float*)alloc((size_t)n_p * 128 * 4);
  // AGh+AGl region (contiguous); AGf (layer-1 f32 AG, K<=78 -> 64 MB) ALIASES it.
  unsigned short* AGh = (unsigned short*)alloc((size_t)n_p * 128 * 2);
  unsigned short* AGl = (unsigned short*)alloc((size_t)n_p * 128 * 2);
  float* AGf    = (float*)AGh;
  unsigned short* W2th = (unsigned short*)alloc(64 * 128 * 2);
  unsigned short* W2tl = (unsigned short*)alloc(64 * 128 * 2);
  unsigned short* W3th = (unsigned short*)alloc(128 * 256 * 2);
  unsigned short* W3tl = (unsigned short*)alloc(128 * 256 * 2);
  int* bsum     = (int*)alloc(1024 * 4);
  int* cur_p    = (int*)alloc((size_t)n_p * 4);
  int* row_p    = (int*)alloc(((size_t)n_p + 1) * 4);
  int* esrc_p   = (int*)alloc((size_t)E_p * 4);
  int* cur_l    = (int*)alloc((size_t)n_l * 4);
  int* row_l    = (int*)alloc(((size_t)n_l + 1) * 4);
  int* esrc_l   = (int*)alloc((size_t)E_l * 4);
  float* fc1o   = F;                 // branches done before the FC stack
  float* fc2o   = F + 512 * 1024;
  (void)ws_size; (void)n_in; (void)out_size;

  hipMemsetAsync(pooled, 0, 512 * 512 * 4, stream);

  auto gemm64 = [&](const float* A, const float* W, const float* b, float* Y,
                    int n, int Kin, int Kout, int ystride) {
    dim3 grd((n + 63) / 64, Kout / 64);
    k_gemm_t<true><<<grd, 256, 0, stream>>>(A, W, b, Y, n, Kin, Kout, ystride);
  };

  auto branch = [&](const float* x0, const int* ei, const int* batch, int n, int E, int IN,
                    const float* W1, const float* b1, const float* W2, const float* b2,
                    const float* W3, const float* b3, float* dinv, float* cnt,
                    int* cursor, int* rowptr, int* esrc, int colbase) {
    const int* src = ei;
    const int* dst = ei + E;
    const int nb = (n + 255) / 256;
    k_fill<<<nb, 256, 0, stream>>>(dinv, 1.0f, n);
    k_deg<<<(E + 255) / 256, 256, 0, stream>>>(dinv, dst, E);
    k_count_sorted<<<2, 256, 0, stream>>>(cnt, batch, n, 512);
    k_scan1<<<nb, 256, 0, stream>>>(dinv, cursor, bsum, n);
    k_scan2<<<1, 1024, 0, stream>>>(bsum, nb);
    k_scan3<<<(n + 256) / 256 + 1, 256, 0, stream>>>(rowptr, cursor, bsum, dinv, n, E);
    k_fill_csr<<<(E + 255) / 256, 256, 0, stream>>>(src, dst, cursor, esrc, E);
    // W pre-split
    k_wsplit<<<(64 * 128 + 255) / 256, 256, 0, stream>>>(W2, W2th, W2tl, 64, 128);
    k_wsplit<<<(128 * 256 + 255) / 256, 256, 0, stream>>>(W3, W3th, W3tl, 128, 256);
    int gw = (n * 64 + 255) / 256;
    // layer 1 (ragged Kin) -> f32 64-tile
    k_agg<false><<<gw, 256, 0, stream>>>(AGf, nullptr, nullptr, x0, rowptr, esrc, dinv, n, IN);
    gemm64(AGf, W1, b1, F, n, IN, 64, 64);
    // layer 2: split agg -> MFMA GEMM (K=64 -> 128)
    k_agg<true><<<gw, 256, 0, stream>>>(nullptr, AGh, AGl, F, rowptr, esrc, dinv, n, 64);
    {
      dim3 grd((n + 127) / 128, 1);
      k_gemm_mfma<false><<<grd, 256, 0, stream>>>(AGh, AGl, W2th, W2tl, b2, F,
                                                  n, 64, 128, nullptr, 128, 0);
    }
    // layer 3: split agg -> MFMA GEMM (K=128 -> 256) + fused mean-pool numerator
    k_agg<true><<<gw, 256, 0, stream>>>(nullptr, AGh, AGl, F, rowptr, esrc, dinv, n, 128);
    {
      dim3 grd((n + 127) / 128, 2);
      k_gemm_mfma<true><<<grd, 256, 0, stream>>>(AGh, AGl, W3th, W3tl, b3, pooled,
                                                 n, 128, 256, batch, 512, colbase);
    }
  };

  branch(p_x, p_ei, p_bt, n_p, E_p, IN_P, pW1, pb1, pW2, pb2, pW3, pb3,
         dinv_p, cnt_p, cur_p, row_p, esrc_p, 0);
  branch(l_x, l_ei, l_bt, n_l, E_l, IN_L, lW1, lb1, lW2, lb2, lW3, lb3,
         dinv_l, cnt_l, cur_l, row_l, esrc_l, 256);

  k_pool_div<<<(512 * 256 + 255) / 256, 256, 0, stream>>>(pooled, cnt_p, 0);
  k_pool_div<<<(512 * 256 + 255) / 256, 256, 0, stream>>>(pooled, cnt_l, 256);

  // FC stack (f32 path)
  gemm64(pooled, fc1W, fc1b, fc1o, 512, 512, 1024, 1024);
  gemm64(fc1o, fc2W, fc2b, fc2o, 512, 1024, 512, 512);
  k_out<<<512, 64, 0, stream>>>((float*)d_out, fc2o, oW, ob);
}

// Round 9
// 1281.433 us; speedup vs baseline: 1.4945x; 1.2192x over previous
//
#include <hip/hip_runtime.h>

typedef __attribute__((ext_vector_type(8))) short short8;
typedef __attribute__((ext_vector_type(16))) float f32x16;

// ---------------- bf16 split helpers ----------------

__device__ __forceinline__ unsigned short f2bf_rne(float f) {
  unsigned u = __float_as_uint(f);
  u += 0x7fffu + ((u >> 16) & 1u);
  return (unsigned short)(u >> 16);
}
__device__ __forceinline__ float bf2f(unsigned short h) {
  return __uint_as_float(((unsigned)h) << 16);
}

// ---------------- small helper kernels ----------------

static __global__ void k_fill(float* __restrict__ p, float v, int n) {
  int i = blockIdx.x * blockDim.x + threadIdx.x;
  if (i < n) p[i] = v;
}

static __global__ void k_deg(float* __restrict__ deg, const int* __restrict__ dst, int E) {
  int e = blockIdx.x * blockDim.x + threadIdx.x;
  if (e < E) atomicAdd(&deg[dst[e]], 1.0f);
}

// cnt[b] = run-length of b in SORTED batch (two binary searches, no atomics)
static __global__ void k_count_sorted(float* __restrict__ cnt, const int* __restrict__ batch,
                                      int n, int nb) {
  int b = blockIdx.x * blockDim.x + threadIdx.x;
  if (b >= nb) return;
  int lo = 0, hi = n;
  while (lo < hi) { int mid = (lo + hi) >> 1; if (batch[mid] < b) lo = mid + 1; else hi = mid; }
  int start = lo;
  lo = 0; hi = n;
  while (lo < hi) { int mid = (lo + hi) >> 1; if (batch[mid] < b + 1) lo = mid + 1; else hi = mid; }
  cnt[b] = (float)(lo - start);
}

// ---------------- CSR build ----------------

static __global__ void k_scan1(const float* __restrict__ degf, int* __restrict__ ex,
                               int* __restrict__ bsum, int n) {
  __shared__ int sm[256];
  int i = blockIdx.x * 256 + threadIdx.x;
  int v = (i < n) ? ((int)degf[i] - 1) : 0;
  sm[threadIdx.x] = v;
  __syncthreads();
  for (int off = 1; off < 256; off <<= 1) {
    int t = (threadIdx.x >= (unsigned)off) ? sm[threadIdx.x - off] : 0;
    __syncthreads();
    sm[threadIdx.x] += t;
    __syncthreads();
  }
  if (i < n) ex[i] = sm[threadIdx.x] - v;
  if (threadIdx.x == 255) bsum[blockIdx.x] = sm[255];
}

static __global__ void k_scan2(int* __restrict__ bsum, int nb) {
  __shared__ int sm[1024];
  __shared__ int carry;
  if (threadIdx.x == 0) carry = 0;
  __syncthreads();
  for (int base = 0; base < nb; base += 1024) {
    int i = base + threadIdx.x;
    int v = (i < nb) ? bsum[i] : 0;
    sm[threadIdx.x] = v;
    __syncthreads();
    for (int off = 1; off < 1024; off <<= 1) {
      int t = (threadIdx.x >= (unsigned)off) ? sm[threadIdx.x - off] : 0;
      __syncthreads();
      sm[threadIdx.x] += t;
      __syncthreads();
    }
    if (i < nb) bsum[i] = sm[threadIdx.x] + carry;
    __syncthreads();
    if (threadIdx.x == 0) carry += sm[1023];
    __syncthreads();
  }
}

static __global__ void k_scan3(int* __restrict__ rowptr, int* __restrict__ cursor_ex,
                               const int* __restrict__ bsum, float* __restrict__ dinv,
                               int n, int E) {
  int i = blockIdx.x * 256 + threadIdx.x;
  if (i > n) return;
  if (i == n) { rowptr[n] = E; return; }
  int add = blockIdx.x ? bsum[blockIdx.x - 1] : 0;
  int r = cursor_ex[i] + add;
  rowptr[i] = r;
  cursor_ex[i] = r;
  dinv[i] = 1.0f / sqrtf(dinv[i]);
}

static __global__ void k_fill_csr(const int* __restrict__ src, const int* __restrict__ dst,
                                  int* __restrict__ cursor, int* __restrict__ esrc, int E) {
  int e = blockIdx.x * 256 + threadIdx.x;
  if (e >= E) return;
  int pos = atomicAdd(&cursor[dst[e]], 1);
  esrc[pos] = src[e];
}

// ---------------- pull aggregation, f32 out (layer 1, ragged K <= 128) ----------------
static __global__ void __launch_bounds__(256)
k_agg(float* __restrict__ AG, const float* __restrict__ X,
      const int* __restrict__ rowptr, const int* __restrict__ esrc,
      const float* __restrict__ dinv, int n, int K) {
  int wid = (blockIdx.x * blockDim.x + threadIdx.x) >> 6;
  int lane = threadIdx.x & 63;
  if (wid >= n) return;
  int rs = rowptr[wid], re = rowptr[wid + 1];
  float dv = dinv[wid];
  const float* xr = X + (size_t)wid * K;
  float a0 = (lane < K) ? xr[lane] * dv * dv : 0.0f;
  float a1 = (64 + lane < K) ? xr[64 + lane] * dv * dv : 0.0f;
  for (int e = rs; e < re; ++e) {
    int s = esrc[e];
    float w = dinv[s] * dv;
    const float* xs = X + (size_t)s * K;
    if (lane < K) a0 = fmaf(xs[lane], w, a0);
    if (64 + lane < K) a1 = fmaf(xs[64 + lane], w, a1);
  }
  float* ar = AG + (size_t)wid * K;
  if (lane < K) ar[lane] = a0;
  if (64 + lane < K) ar[64 + lane] = a1;
}

// ---------------- pull aggregation, split-bf16 out, sub-wave group per node ----------------
// Group = 2^LG lanes; K = 4*2^LG (each lane owns one float4). 64>>LG nodes per wave ->
// more independent edge loops in flight (gather-latency hiding) + 16B coalesced loads.
template<int LG>
static __global__ void __launch_bounds__(256)
k_agg_split(unsigned short* __restrict__ AGh, unsigned short* __restrict__ AGl,
            const float* __restrict__ X,
            const int* __restrict__ rowptr, const int* __restrict__ esrc,
            const float* __restrict__ dinv, int n) {
  const int K = (1 << LG) * 4;
  int gid = (blockIdx.x * blockDim.x + threadIdx.x) >> LG;   // node id
  int gl = threadIdx.x & ((1 << LG) - 1);                    // lane within group
  if (gid >= n) return;
  int rs = rowptr[gid], re = rowptr[gid + 1];
  float dv = dinv[gid];
  float4 a = *(const float4*)(X + (size_t)gid * K + gl * 4);
  float dv2 = dv * dv;
  a.x *= dv2; a.y *= dv2; a.z *= dv2; a.w *= dv2;
  for (int e = rs; e < re; ++e) {
    int s = esrc[e];
    float w = dinv[s] * dv;
    float4 xs = *(const float4*)(X + (size_t)s * K + gl * 4);
    a.x = fmaf(xs.x, w, a.x);
    a.y = fmaf(xs.y, w, a.y);
    a.z = fmaf(xs.z, w, a.z);
    a.w = fmaf(xs.w, w, a.w);
  }
  size_t base = (size_t)gid * K + gl * 4;
  unsigned short h0 = f2bf_rne(a.x), h1 = f2bf_rne(a.y), h2 = f2bf_rne(a.z), h3 = f2bf_rne(a.w);
  ushort4 hv = {h0, h1, h2, h3};
  ushort4 lv = {f2bf_rne(a.x - bf2f(h0)), f2bf_rne(a.y - bf2f(h1)),
                f2bf_rne(a.z - bf2f(h2)), f2bf_rne(a.w - bf2f(h3))};
  *(ushort4*)&AGh[base] = hv;
  *(ushort4*)&AGl[base] = lv;
}

// ---------------- W pre-split + transpose:  Wt[c][k] = split(W[k][c]) ----------------
static __global__ void k_wsplit(const float* __restrict__ W,
                                unsigned short* __restrict__ Wth, unsigned short* __restrict__ Wtl,
                                int Kin, int Kout) {
  int idx = blockIdx.x * blockDim.x + threadIdx.x;
  if (idx >= Kin * Kout) return;
  int k = idx / Kout, c = idx - k * Kout;
  float v = W[idx];
  unsigned short h = f2bf_rne(v);
  Wth[(size_t)c * Kin + k] = h;
  Wtl[(size_t)c * Kin + k] = f2bf_rne(v - bf2f(h));
}

// ---------------- split-bf16 MFMA GEMM ----------------
template<bool POOL>
static __global__ void __launch_bounds__(256)
k_gemm_mfma(const unsigned short* __restrict__ Ah, const unsigned short* __restrict__ Al,
            const unsigned short* __restrict__ Bth, const unsigned short* __restrict__ Btl,
            const float* __restrict__ bias, float* __restrict__ Y,
            int n, int K, int Kout,
            const int* __restrict__ batch, int ystride, int colbase) {
  __shared__ __align__(16) unsigned short sAh[128 * 32];
  __shared__ __align__(16) unsigned short sAl[128 * 32];
  __shared__ __align__(16) unsigned short sBh[128 * 32];
  __shared__ __align__(16) unsigned short sBl[128 * 32];

  const int tid = threadIdx.x;
  const int lane = tid & 63;
  const int wid = tid >> 6;
  const int wr = wid >> 1, wc = wid & 1;
  const int g = lane >> 5;           // k-half selector within frag
  const int r0 = blockIdx.x * 128;
  const int c0 = blockIdx.y * 128;

  f32x16 acc[2][2] = {};

  const int srow = tid & 127;        // staging row (A) / col (B)
  const int q0 = tid >> 7;           // 0/1

  const int nch = K / 32;
  for (int ch = 0; ch < nch; ++ch) {
    const int k0 = ch * 32;
    if (ch) __syncthreads();
    {
      bool rok = (r0 + srow) < n;
      size_t abase = (size_t)(r0 + srow) * K + k0;
      size_t bbase = (size_t)(c0 + srow) * K + k0;
      int swz = ((srow >> 1) & 3) << 3;
#pragma unroll
      for (int qq = 0; qq < 2; ++qq) {
        int q = q0 + 2 * qq;
        int sidx = srow * 32 + ((q * 8) ^ swz);
        short8 vh = {}, vl = {};
        if (rok) {
          vh = *(const short8*)&Ah[abase + q * 8];
          vl = *(const short8*)&Al[abase + q * 8];
        }
        *(short8*)&sAh[sidx] = vh;
        *(short8*)&sAl[sidx] = vl;
        *(short8*)&sBh[sidx] = *(const short8*)&Bth[bbase + q * 8];
        *(short8*)&sBl[sidx] = *(const short8*)&Btl[bbase + q * 8];
      }
    }
    __syncthreads();
#pragma unroll
    for (int kk = 0; kk < 2; ++kk) {
      short8 ah[2], al[2], bh[2], bl[2];
#pragma unroll
      for (int f = 0; f < 2; ++f) {
        int ra = wr * 64 + f * 32 + (lane & 31);
        int ka = (kk * 16 + g * 8) ^ (((ra >> 1) & 3) << 3);
        ah[f] = *(const short8*)&sAh[ra * 32 + ka];
        al[f] = *(const short8*)&sAl[ra * 32 + ka];
        int rb = wc * 64 + f * 32 + (lane & 31);
        int kb = (kk * 16 + g * 8) ^ (((rb >> 1) & 3) << 3);
        bh[f] = *(const short8*)&sBh[rb * 32 + kb];
        bl[f] = *(const short8*)&sBl[rb * 32 + kb];
      }
#pragma unroll
      for (int fa = 0; fa < 2; ++fa)
#pragma unroll
        for (int fb = 0; fb < 2; ++fb) {
          acc[fa][fb] = __builtin_amdgcn_mfma_f32_32x32x16_bf16(ah[fa], bh[fb], acc[fa][fb], 0, 0, 0);
          acc[fa][fb] = __builtin_amdgcn_mfma_f32_32x32x16_bf16(ah[fa], bl[fb], acc[fa][fb], 0, 0, 0);
          acc[fa][fb] = __builtin_amdgcn_mfma_f32_32x32x16_bf16(al[fa], bh[fb], acc[fa][fb], 0, 0, 0);
        }
    }
  }

  // epilogue. C/D layout (HW-verified): col = lane&31, row = (reg&3)+8*(reg>>2)+4*(lane>>5)
  if (!POOL) {
#pragma unroll
    for (int fa = 0; fa < 2; ++fa)
#pragma unroll
      for (int fb = 0; fb < 2; ++fb) {
        int col = c0 + wc * 64 + fb * 32 + (lane & 31);
        float bcol = bias[col];
#pragma unroll
        for (int r = 0; r < 16; ++r) {
          int grow = r0 + wr * 64 + fa * 32 + (r & 3) + 8 * (r >> 2) + 4 * g;
          if (grow < n) {
            float v = fmaxf(acc[fa][fb][r] + bcol, 0.0f);
            Y[(size_t)grow * ystride + col] = v;
          }
        }
      }
  } else {
#pragma unroll
    for (int fa = 0; fa < 2; ++fa)
#pragma unroll
      for (int fb = 0; fb < 2; ++fb) {
        int col = colbase + c0 + wc * 64 + fb * 32 + (lane & 31);
        float bcol = bias[c0 + wc * 64 + fb * 32 + (lane & 31)];
        float s = 0.0f;
        int cur = -1;
#pragma unroll
        for (int r = 0; r < 16; ++r) {
          int grow = r0 + wr * 64 + fa * 32 + (r & 3) + 8 * (r >> 2) + 4 * g;
          if (grow < n) {
            int b = batch[grow];
            if (b != cur) {
              if (cur >= 0 && s != 0.0f)
                atomicAdd(&Y[(size_t)cur * ystride + col], s);
              cur = b;
              s = 0.0f;
            }
            s += fmaxf(acc[fa][fb][r] + bcol, 0.0f);
          }
        }
        if (cur >= 0 && s != 0.0f)
          atomicAdd(&Y[(size_t)cur * ystride + col], s);
      }
  }
}

// ---------------- 64x64 tiled f32 GEMM (L1 ragged-K + FC stack) ----------------
template<bool RELU>
static __global__ void __launch_bounds__(256)
k_gemm_t(const float* __restrict__ A, const float* __restrict__ W,
         const float* __restrict__ bias, float* __restrict__ Y,
         int n, int Kin, int Kout, int ystride) {
  __shared__ float As[32][68];
  __shared__ float Ws[32][68];

  const int tid = threadIdx.x;
  const int tx = tid & 15, ty = tid >> 4;
  const int r0 = blockIdx.x * 64;
  const int c0 = blockIdx.y * 64;

  float acc[4][4] = {};

  const int ar = tid & 63;
  const int akg = (tid >> 6) * 8;
  const int wkk = tid & 31;
  const int wcg = (tid >> 5) * 8;

  const int nch = (Kin + 31) / 32;
  for (int ch = 0; ch < nch; ++ch) {
    const int k0 = ch * 32;
    {
      int grow = r0 + ar;
      bool rok = grow < n;
      const float* arow = A + (size_t)grow * Kin;
#pragma unroll
      for (int i = 0; i < 8; ++i) {
        int k = k0 + akg + i;
        As[akg + i][ar] = (rok && k < Kin) ? arow[k] : 0.0f;
      }
    }
    {
      int gk = k0 + wkk;
      float4 v0 = make_float4(0.f, 0.f, 0.f, 0.f), v1 = v0;
      if (gk < Kin) {
        const float* wp = W + (size_t)gk * Kout + c0 + wcg;
        v0 = *(const float4*)wp;
        v1 = *(const float4*)(wp + 4);
      }
      *(float4*)&Ws[wkk][wcg] = v0;
      *(float4*)&Ws[wkk][wcg + 4] = v1;
    }
    __syncthreads();
#pragma unroll
    for (int k = 0; k < 32; ++k) {
      float4 a4 = *(const float4*)&As[k][ty * 4];
      float4 w4 = *(const float4*)&Ws[k][tx * 4];
      float av[4] = {a4.x, a4.y, a4.z, a4.w};
      float wv[4] = {w4.x, w4.y, w4.z, w4.w};
#pragma unroll
      for (int i = 0; i < 4; ++i)
#pragma unroll
        for (int j = 0; j < 4; ++j)
          acc[i][j] = fmaf(av[i], wv[j], acc[i][j]);
    }
    __syncthreads();
  }

  float4 bv = *(const float4*)&bias[c0 + tx * 4];
  float bb[4] = {bv.x, bv.y, bv.z, bv.w};
#pragma unroll
  for (int i = 0; i < 4; ++i) {
    int row = r0 + ty * 4 + i;
    if (row < n) {
      float o[4];
#pragma unroll
      for (int j = 0; j < 4; ++j) {
        o[j] = acc[i][j] + bb[j];
        if (RELU) o[j] = fmaxf(o[j], 0.0f);
      }
      *(float4*)&Y[(size_t)row * ystride + c0 + tx * 4] = make_float4(o[0], o[1], o[2], o[3]);
    }
  }
}

// pooled[b, colbase+c] /= max(cnt[b],1)
static __global__ void k_pool_div(float* __restrict__ pooled, const float* __restrict__ cnt,
                                  int colbase) {
  int i = blockIdx.x * blockDim.x + threadIdx.x;
  if (i >= 512 * 256) return;
  int b = i >> 8;
  int c = i & 255;
  pooled[b * 512 + colbase + c] /= fmaxf(cnt[b], 1.0f);
}

// out[row] = X[row,:512] . w + b
static __global__ void k_out(float* __restrict__ out, const float* __restrict__ X,
                             const float* __restrict__ w, const float* __restrict__ b) {
  int row = blockIdx.x;
  int lane = threadIdx.x;
  float acc = 0.f;
  for (int k = lane; k < 512; k += 64)
    acc = fmaf(X[row * 512 + k], w[k], acc);
#pragma unroll
  for (int off = 32; off; off >>= 1) acc += __shfl_down(acc, off);
  if (lane == 0) out[row] = acc + b[0];
}

// ---------------- launch ----------------

extern "C" void kernel_launch(void* const* d_in, const int* in_sizes, int n_in,
                              void* d_out, int out_size, void* d_ws, size_t ws_size,
                              hipStream_t stream) {
  const float* p_x  = (const float*)d_in[0];
  const int*   p_ei = (const int*)d_in[1];
  const int*   p_bt = (const int*)d_in[2];
  const float* l_x  = (const float*)d_in[3];
  const int*   l_ei = (const int*)d_in[4];
  const int*   l_bt = (const int*)d_in[5];
  const float* pW1 = (const float*)d_in[6],  *pb1 = (const float*)d_in[7];
  const float* pW2 = (const float*)d_in[8],  *pb2 = (const float*)d_in[9];
  const float* pW3 = (const float*)d_in[10], *pb3 = (const float*)d_in[11];
  const float* lW1 = (const float*)d_in[12], *lb1 = (const float*)d_in[13];
  const float* lW2 = (const float*)d_in[14], *lb2 = (const float*)d_in[15];
  const float* lW3 = (const float*)d_in[16], *lb3 = (const float*)d_in[17];
  const float* fc1W = (const float*)d_in[18], *fc1b = (const float*)d_in[19];
  const float* fc2W = (const float*)d_in[20], *fc2b = (const float*)d_in[21];
  const float* oW  = (const float*)d_in[22], *ob  = (const float*)d_in[23];

  const int n_p = in_sizes[2], n_l = in_sizes[5];
  const int E_p = in_sizes[1] / 2, E_l = in_sizes[4] / 2;
  const int IN_P = in_sizes[0] / n_p, IN_L = in_sizes[3] / n_l;   // 41, 78

  char* wsc = (char*)d_ws;
  size_t off = 0;
  auto alloc = [&](size_t bytes) -> void* {
    void* p = wsc + off;
    off = (off + bytes + 255) & ~(size_t)255;
    return p;
  };
  float* dinv_p = (float*)alloc((size_t)n_p * 4);
  float* dinv_l = (float*)alloc((size_t)n_l * 4);
  float* cnt_p  = (float*)alloc(512 * 4);
  float* cnt_l  = (float*)alloc(512 * 4);
  float* pooled = (float*)alloc(512 * 512 * 4);
  float* F      = (float*)alloc((size_t)n_p * 128 * 4);
  // AGh+AGl region (contiguous); AGf (layer-1 f32 AG, K<=78 -> 64 MB) ALIASES it.
  unsigned short* AGh = (unsigned short*)alloc((size_t)n_p * 128 * 2);
  unsigned short* AGl = (unsigned short*)alloc((size_t)n_p * 128 * 2);
  float* AGf    = (float*)AGh;
  unsigned short* W2th = (unsigned short*)alloc(64 * 128 * 2);
  unsigned short* W2tl = (unsigned short*)alloc(64 * 128 * 2);
  unsigned short* W3th = (unsigned short*)alloc(128 * 256 * 2);
  unsigned short* W3tl = (unsigned short*)alloc(128 * 256 * 2);
  int* bsum     = (int*)alloc(1024 * 4);
  int* cur_p    = (int*)alloc((size_t)n_p * 4);
  int* row_p    = (int*)alloc(((size_t)n_p + 1) * 4);
  int* esrc_p   = (int*)alloc((size_t)E_p * 4);
  int* cur_l    = (int*)alloc((size_t)n_l * 4);
  int* row_l    = (int*)alloc(((size_t)n_l + 1) * 4);
  int* esrc_l   = (int*)alloc((size_t)E_l * 4);
  float* fc1o   = F;                 // branches done before the FC stack
  float* fc2o   = F + 512 * 1024;
  (void)ws_size; (void)n_in; (void)out_size;

  hipMemsetAsync(pooled, 0, 512 * 512 * 4, stream);

  auto gemm64 = [&](const float* A, const float* W, const float* b, float* Y,
                    int n, int Kin, int Kout, int ystride) {
    dim3 grd((n + 63) / 64, Kout / 64);
    k_gemm_t<true><<<grd, 256, 0, stream>>>(A, W, b, Y, n, Kin, Kout, ystride);
  };

  auto branch = [&](const float* x0, const int* ei, const int* batch, int n, int E, int IN,
                    const float* W1, const float* b1, const float* W2, const float* b2,
                    const float* W3, const float* b3, float* dinv, float* cnt,
                    int* cursor, int* rowptr, int* esrc, int colbase) {
    const int* src = ei;
    const int* dst = ei + E;
    const int nb = (n + 255) / 256;
    k_fill<<<nb, 256, 0, stream>>>(dinv, 1.0f, n);
    k_deg<<<(E + 255) / 256, 256, 0, stream>>>(dinv, dst, E);
    k_count_sorted<<<2, 256, 0, stream>>>(cnt, batch, n, 512);
    k_scan1<<<nb, 256, 0, stream>>>(dinv, cursor, bsum, n);
    k_scan2<<<1, 1024, 0, stream>>>(bsum, nb);
    k_scan3<<<(n + 256) / 256 + 1, 256, 0, stream>>>(rowptr, cursor, bsum, dinv, n, E);
    k_fill_csr<<<(E + 255) / 256, 256, 0, stream>>>(src, dst, cursor, esrc, E);
    // W pre-split
    k_wsplit<<<(64 * 128 + 255) / 256, 256, 0, stream>>>(W2, W2th, W2tl, 64, 128);
    k_wsplit<<<(128 * 256 + 255) / 256, 256, 0, stream>>>(W3, W3th, W3tl, 128, 256);
    // layer 1 (ragged Kin) -> f32 64-tile
    k_agg<<<(n * 64 + 255) / 256, 256, 0, stream>>>(AGf, x0, rowptr, esrc, dinv, n, IN);
    gemm64(AGf, W1, b1, F, n, IN, 64, 64);
    // layer 2: split agg (16 lanes/node, K=64) -> MFMA GEMM (K=64 -> 128)
    k_agg_split<4><<<(n * 16 + 255) / 256, 256, 0, stream>>>(AGh, AGl, F, rowptr, esrc, dinv, n);
    {
      dim3 grd((n + 127) / 128, 1);
      k_gemm_mfma<false><<<grd, 256, 0, stream>>>(AGh, AGl, W2th, W2tl, b2, F,
                                                  n, 64, 128, nullptr, 128, 0);
    }
    // layer 3: split agg (32 lanes/node, K=128) -> MFMA GEMM (K=128 -> 256) + fused pool
    k_agg_split<5><<<(n * 32 + 255) / 256, 256, 0, stream>>>(AGh, AGl, F, rowptr, esrc, dinv, n);
    {
      dim3 grd((n + 127) / 128, 2);
      k_gemm_mfma<true><<<grd, 256, 0, stream>>>(AGh, AGl, W3th, W3tl, b3, pooled,
                                                 n, 128, 256, batch, 512, colbase);
    }
  };

  branch(p_x, p_ei, p_bt, n_p, E_p, IN_P, pW1, pb1, pW2, pb2, pW3, pb3,
         dinv_p, cnt_p, cur_p, row_p, esrc_p, 0);
  branch(l_x, l_ei, l_bt, n_l, E_l, IN_L, lW1, lb1, lW2, lb2, lW3, lb3,
         dinv_l, cnt_l, cur_l, row_l, esrc_l, 256);

  k_pool_div<<<(512 * 256 + 255) / 256, 256, 0, stream>>>(pooled, cnt_p, 0);
  k_pool_div<<<(512 * 256 + 255) / 256, 256, 0, stream>>>(pooled, cnt_l, 256);

  // FC stack (f32 path)
  gemm64(pooled, fc1W, fc1b, fc1o, 512, 512, 1024, 1024);
  gemm64(fc1o, fc2W, fc2b, fc2o, 512, 1024, 512, 512);
  k_out<<<512, 64, 0, stream>>>((float*)d_out, fc2o, oW, ob);
}

// Round 11
// 1199.525 us; speedup vs baseline: 1.5965x; 1.0683x over previous
//
#include <hip/hip_runtime.h>

typedef __attribute__((ext_vector_type(8))) short short8;
typedef __attribute__((ext_vector_type(16))) float f32x16;

// ---------------- bf16 split helpers ----------------

__device__ __forceinline__ unsigned short f2bf_rne(float f) {
  unsigned u = __float_as_uint(f);
  u += 0x7fffu + ((u >> 16) & 1u);
  return (unsigned short)(u >> 16);
}
__device__ __forceinline__ float bf2f(unsigned short h) {
  return __uint_as_float(((unsigned)h) << 16);
}

// ---------------- small helper kernels ----------------

static __global__ void k_fill(float* __restrict__ p, float v, int n) {
  int i = blockIdx.x * blockDim.x + threadIdx.x;
  if (i < n) p[i] = v;
}

static __global__ void k_deg(float* __restrict__ deg, const int* __restrict__ dst, int E) {
  int e = blockIdx.x * blockDim.x + threadIdx.x;
  if (e < E) atomicAdd(&deg[dst[e]], 1.0f);
}

// cnt[b] = run-length of b in SORTED batch (two binary searches, no atomics)
static __global__ void k_count_sorted(float* __restrict__ cnt, const int* __restrict__ batch,
                                      int n, int nb) {
  int b = blockIdx.x * blockDim.x + threadIdx.x;
  if (b >= nb) return;
  int lo = 0, hi = n;
  while (lo < hi) { int mid = (lo + hi) >> 1; if (batch[mid] < b) lo = mid + 1; else hi = mid; }
  int start = lo;
  lo = 0; hi = n;
  while (lo < hi) { int mid = (lo + hi) >> 1; if (batch[mid] < b + 1) lo = mid + 1; else hi = mid; }
  cnt[b] = (float)(lo - start);
}

// ---------------- CSR build ----------------

static __global__ void k_scan1(const float* __restrict__ degf, int* __restrict__ ex,
                               int* __restrict__ bsum, int n) {
  __shared__ int sm[256];
  int i = blockIdx.x * 256 + threadIdx.x;
  int v = (i < n) ? ((int)degf[i] - 1) : 0;
  sm[threadIdx.x] = v;
  __syncthreads();
  for (int off = 1; off < 256; off <<= 1) {
    int t = (threadIdx.x >= (unsigned)off) ? sm[threadIdx.x - off] : 0;
    __syncthreads();
    sm[threadIdx.x] += t;
    __syncthreads();
  }
  if (i < n) ex[i] = sm[threadIdx.x] - v;
  if (threadIdx.x == 255) bsum[blockIdx.x] = sm[255];
}

static __global__ void k_scan2(int* __restrict__ bsum, int nb) {
  __shared__ int sm[1024];
  __shared__ int carry;
  if (threadIdx.x == 0) carry = 0;
  __syncthreads();
  for (int base = 0; base < nb; base += 1024) {
    int i = base + threadIdx.x;
    int v = (i < nb) ? bsum[i] : 0;
    sm[threadIdx.x] = v;
    __syncthreads();
    for (int off = 1; off < 1024; off <<= 1) {
      int t = (threadIdx.x >= (unsigned)off) ? sm[threadIdx.x - off] : 0;
      __syncthreads();
      sm[threadIdx.x] += t;
      __syncthreads();
    }
    if (i < nb) bsum[i] = sm[threadIdx.x] + carry;
    __syncthreads();
    if (threadIdx.x == 0) carry += sm[1023];
    __syncthreads();
  }
}

static __global__ void k_scan3(int* __restrict__ rowptr, int* __restrict__ cursor_ex,
                               const int* __restrict__ bsum, float* __restrict__ dinv,
                               int n, int E) {
  int i = blockIdx.x * 256 + threadIdx.x;
  if (i > n) return;
  if (i == n) { rowptr[n] = E; return; }
  int add = blockIdx.x ? bsum[blockIdx.x - 1] : 0;
  int r = cursor_ex[i] + add;
  rowptr[i] = r;
  cursor_ex[i] = r;
  dinv[i] = 1.0f / sqrtf(dinv[i]);
}

static __global__ void k_fill_csr(const int* __restrict__ src, const int* __restrict__ dst,
                                  int* __restrict__ cursor, int* __restrict__ esrc, int E) {
  int e = blockIdx.x * 256 + threadIdx.x;
  if (e >= E) return;
  int pos = atomicAdd(&cursor[dst[e]], 1);
  esrc[pos] = src[e];
}

// ---------------- pull aggregation, f32 out (layer 1, ragged K <= 128) ----------------
static __global__ void __launch_bounds__(256)
k_agg(float* __restrict__ AG, const float* __restrict__ X,
      const int* __restrict__ rowptr, const int* __restrict__ esrc,
      const float* __restrict__ dinv, int n, int K) {
  int wid = (blockIdx.x * blockDim.x + threadIdx.x) >> 6;
  int lane = threadIdx.x & 63;
  if (wid >= n) return;
  int rs = rowptr[wid], re = rowptr[wid + 1];
  float dv = dinv[wid];
  const float* xr = X + (size_t)wid * K;
  float a0 = (lane < K) ? xr[lane] * dv * dv : 0.0f;
  float a1 = (64 + lane < K) ? xr[64 + lane] * dv * dv : 0.0f;
  for (int e = rs; e < re; ++e) {
    int s = esrc[e];
    float w = dinv[s] * dv;
    const float* xs = X + (size_t)s * K;
    if (lane < K) a0 = fmaf(xs[lane], w, a0);
    if (64 + lane < K) a1 = fmaf(xs[64 + lane], w, a1);
  }
  float* ar = AG + (size_t)wid * K;
  if (lane < K) ar[lane] = a0;
  if (64 + lane < K) ar[64 + lane] = a1;
}

// ---------------- pull aggregation, split-bf16 out in MFMA-FRAGMENT layout ----------------
// Fragment layout: AG[((rowblk*NCH + chunk)*32 + row&31)*8 + k&7], rowblk=row>>5, chunk=k>>3.
// A wave's GEMM fragment load then reads 1KB fully-contiguous. Group = 2^LG lanes per node.
template<int LG>
static __global__ void __launch_bounds__(256)
k_agg_split(unsigned short* __restrict__ AGh, unsigned short* __restrict__ AGl,
            const float* __restrict__ X,
            const int* __restrict__ rowptr, const int* __restrict__ esrc,
            const float* __restrict__ dinv, int n) {
  const int K = (1 << LG) * 4;
  const int NCH = K / 8;
  int gid = (blockIdx.x * blockDim.x + threadIdx.x) >> LG;   // node id
  int gl = threadIdx.x & ((1 << LG) - 1);                    // lane within group
  if (gid >= n) return;
  int rs = rowptr[gid], re = rowptr[gid + 1];
  float dv = dinv[gid];
  float4 a = *(const float4*)(X + (size_t)gid * K + gl * 4);
  float dv2 = dv * dv;
  a.x *= dv2; a.y *= dv2; a.z *= dv2; a.w *= dv2;
  for (int e = rs; e < re; ++e) {
    int s = esrc[e];
    float w = dinv[s] * dv;
    float4 xs = *(const float4*)(X + (size_t)s * K + gl * 4);
    a.x = fmaf(xs.x, w, a.x);
    a.y = fmaf(xs.y, w, a.y);
    a.z = fmaf(xs.z, w, a.z);
    a.w = fmaf(xs.w, w, a.w);
  }
  int rb = gid >> 5, r = gid & 31;
  int c = gl >> 1;                 // k-chunk (8 elems)
  int half = (gl & 1) * 4;         // which float4 within the chunk
  size_t base = (((size_t)rb * NCH + c) * 32 + r) * 8 + half;
  unsigned short h0 = f2bf_rne(a.x), h1 = f2bf_rne(a.y), h2 = f2bf_rne(a.z), h3 = f2bf_rne(a.w);
  ushort4 hv = {h0, h1, h2, h3};
  ushort4 lv = {f2bf_rne(a.x - bf2f(h0)), f2bf_rne(a.y - bf2f(h1)),
                f2bf_rne(a.z - bf2f(h2)), f2bf_rne(a.w - bf2f(h3))};
  *(ushort4*)&AGh[base] = hv;
  *(ushort4*)&AGl[base] = lv;
}

// ---------------- W pre-split into the same fragment layout (cols play "rows") ----------------
static __global__ void k_wsplit(const float* __restrict__ W,
                                unsigned short* __restrict__ Wth, unsigned short* __restrict__ Wtl,
                                int Kin, int Kout) {
  int idx = blockIdx.x * blockDim.x + threadIdx.x;
  if (idx >= Kin * Kout) return;
  int k = idx / Kout, c = idx - k * Kout;
  float v = W[idx];
  unsigned short h = f2bf_rne(v);
  int cb = c >> 5, c31 = c & 31, ch = k >> 3, k7 = k & 7;
  size_t base = (((size_t)cb * (Kin / 8) + ch) * 32 + c31) * 8 + k7;
  Wth[base] = h;
  Wtl[base] = f2bf_rne(v - bf2f(h));
}

// ---------------- split-bf16 MFMA GEMM: NO LDS, NO BARRIERS ----------------
// Operands pre-arranged in fragment layout; every fragment load is a contiguous
// 1KB wave read (A streams HBM/L3, B is L2-resident weights).
// Block 128x128 (grid.y tiles Kout), 4 waves (2x2), wave 64x64 = 2x2 frags 32x32x16.
// 3-term split: Ah*Bh + Ah*Bl + Al*Bh.
template<int K, bool POOL>
static __global__ void __launch_bounds__(256)
k_gemm_mfma(const unsigned short* __restrict__ Ah, const unsigned short* __restrict__ Al,
            const unsigned short* __restrict__ Bth, const unsigned short* __restrict__ Btl,
            const float* __restrict__ bias, float* __restrict__ Y,
            int n, int Kout,
            const int* __restrict__ batch, int ystride, int colbase) {
  const int NCH = K / 8;
  const int NKK = K / 16;
  const int tid = threadIdx.x;
  const int lane = tid & 63;
  const int wid = tid >> 6;
  const int wr = wid >> 1, wc = wid & 1;
  const int g = lane >> 5;
  const int l31 = lane & 31;
  const int r0 = blockIdx.x * 128;
  const int c0 = blockIdx.y * 128;
  const int rb0 = (r0 >> 5) + wr * 2;   // this wave's two A row-blocks
  const int cb0 = (c0 >> 5) + wc * 2;   // this wave's two B col-blocks

  f32x16 acc[2][2] = {};

#pragma unroll
  for (int kk = 0; kk < NKK; ++kk) {
    const int ch = 2 * kk + g;
    short8 ah[2], al[2], bh[2], bl[2];
#pragma unroll
    for (int f = 0; f < 2; ++f) {
      size_t aoff = (((size_t)(rb0 + f) * NCH + ch) * 32 + l31) * 8;
      ah[f] = *(const short8*)&Ah[aoff];
      al[f] = *(const short8*)&Al[aoff];
      size_t boff = (((size_t)(cb0 + f) * NCH + ch) * 32 + l31) * 8;
      bh[f] = *(const short8*)&Bth[boff];
      bl[f] = *(const short8*)&Btl[boff];
    }
#pragma unroll
    for (int fa = 0; fa < 2; ++fa)
#pragma unroll
      for (int fb = 0; fb < 2; ++fb) {
        acc[fa][fb] = __builtin_amdgcn_mfma_f32_32x32x16_bf16(ah[fa], bh[fb], acc[fa][fb], 0, 0, 0);
        acc[fa][fb] = __builtin_amdgcn_mfma_f32_32x32x16_bf16(ah[fa], bl[fb], acc[fa][fb], 0, 0, 0);
        acc[fa][fb] = __builtin_amdgcn_mfma_f32_32x32x16_bf16(al[fa], bh[fb], acc[fa][fb], 0, 0, 0);
      }
  }

  // epilogue. C/D layout (HW-verified): col = lane&31, row = (reg&3)+8*(reg>>2)+4*(lane>>5)
  if (!POOL) {
#pragma unroll
    for (int fa = 0; fa < 2; ++fa)
#pragma unroll
      for (int fb = 0; fb < 2; ++fb) {
        int col = c0 + wc * 64 + fb * 32 + l31;
        float bcol = bias[col];
#pragma unroll
        for (int r = 0; r < 16; ++r) {
          int grow = r0 + wr * 64 + fa * 32 + (r & 3) + 8 * (r >> 2) + 4 * g;
          if (grow < n) {
            float v = fmaxf(acc[fa][fb][r] + bcol, 0.0f);
            Y[(size_t)grow * ystride + col] = v;
          }
        }
      }
  } else {
#pragma unroll
    for (int fa = 0; fa < 2; ++fa)
#pragma unroll
      for (int fb = 0; fb < 2; ++fb) {
        int col = colbase + c0 + wc * 64 + fb * 32 + l31;
        float bcol = bias[c0 + wc * 64 + fb * 32 + l31];
        float s = 0.0f;
        int cur = -1;
#pragma unroll
        for (int r = 0; r < 16; ++r) {
          int grow = r0 + wr * 64 + fa * 32 + (r & 3) + 8 * (r >> 2) + 4 * g;
          if (grow < n) {
            int b = batch[grow];
            if (b != cur) {
              if (cur >= 0 && s != 0.0f)
                atomicAdd(&Y[(size_t)cur * ystride + col], s);
              cur = b;
              s = 0.0f;
            }
            s += fmaxf(acc[fa][fb][r] + bcol, 0.0f);
          }
        }
        if (cur >= 0 && s != 0.0f)
          atomicAdd(&Y[(size_t)cur * ystride + col], s);
      }
  }
}

// ---------------- 64x64 tiled f32 GEMM (L1 ragged-K + FC stack) ----------------
template<bool RELU>
static __global__ void __launch_bounds__(256)
k_gemm_t(const float* __restrict__ A, const float* __restrict__ W,
         const float* __restrict__ bias, float* __restrict__ Y,
         int n, int Kin, int Kout, int ystride) {
  __shared__ float As[32][68];
  __shared__ float Ws[32][68];

  const int tid = threadIdx.x;
  const int tx = tid & 15, ty = tid >> 4;
  const int r0 = blockIdx.x * 64;
  const int c0 = blockIdx.y * 64;

  float acc[4][4] = {};

  const int ar = tid & 63;
  const int akg = (tid >> 6) * 8;
  const int wkk = tid & 31;
  const int wcg = (tid >> 5) * 8;

  const int nch = (Kin + 31) / 32;
  for (int ch = 0; ch < nch; ++ch) {
    const int k0 = ch * 32;
    {
      int grow = r0 + ar;
      bool rok = grow < n;
      const float* arow = A + (size_t)grow * Kin;
#pragma unroll
      for (int i = 0; i < 8; ++i) {
        int k = k0 + akg + i;
        As[akg + i][ar] = (rok && k < Kin) ? arow[k] : 0.0f;
      }
    }
    {
      int gk = k0 + wkk;
      float4 v0 = make_float4(0.f, 0.f, 0.f, 0.f), v1 = v0;
      if (gk < Kin) {
        const float* wp = W + (size_t)gk * Kout + c0 + wcg;
        v0 = *(const float4*)wp;
        v1 = *(const float4*)(wp + 4);
      }
      *(float4*)&Ws[wkk][wcg] = v0;
      *(float4*)&Ws[wkk][wcg + 4] = v1;
    }
    __syncthreads();
#pragma unroll
    for (int k = 0; k < 32; ++k) {
      float4 a4 = *(const float4*)&As[k][ty * 4];
      float4 w4 = *(const float4*)&Ws[k][tx * 4];
      float av[4] = {a4.x, a4.y, a4.z, a4.w};
      float wv[4] = {w4.x, w4.y, w4.z, w4.w};
#pragma unroll
      for (int i = 0; i < 4; ++i)
#pragma unroll
        for (int j = 0; j < 4; ++j)
          acc[i][j] = fmaf(av[i], wv[j], acc[i][j]);
    }
    __syncthreads();
  }

  float4 bv = *(const float4*)&bias[c0 + tx * 4];
  float bb[4] = {bv.x, bv.y, bv.z, bv.w};
#pragma unroll
  for (int i = 0; i < 4; ++i) {
    int row = r0 + ty * 4 + i;
    if (row < n) {
      float o[4];
#pragma unroll
      for (int j = 0; j < 4; ++j) {
        o[j] = acc[i][j] + bb[j];
        if (RELU) o[j] = fmaxf(o[j], 0.0f);
      }
      *(float4*)&Y[(size_t)row * ystride + c0 + tx * 4] = make_float4(o[0], o[1], o[2], o[3]);
    }
  }
}

// pooled[b, colbase+c] /= max(cnt[b],1)
static __global__ void k_pool_div(float* __restrict__ pooled, const float* __restrict__ cnt,
                                  int colbase) {
  int i = blockIdx.x * blockDim.x + threadIdx.x;
  if (i >= 512 * 256) return;
  int b = i >> 8;
  int c = i & 255;
  pooled[b * 512 + colbase + c] /= fmaxf(cnt[b], 1.0f);
}

// out[row] = X[row,:512] . w + b
static __global__ void k_out(float* __restrict__ out, const float* __restrict__ X,
                             const float* __restrict__ w, const float* __restrict__ b) {
  int row = blockIdx.x;
  int lane = threadIdx.x;
  float acc = 0.f;
  for (int k = lane; k < 512; k += 64)
    acc = fmaf(X[row * 512 + k], w[k], acc);
#pragma unroll
  for (int off = 32; off; off >>= 1) acc += __shfl_down(acc, off);
  if (lane == 0) out[row] = acc + b[0];
}

// ---------------- launch ----------------

extern "C" void kernel_launch(void* const* d_in, const int* in_sizes, int n_in,
                              void* d_out, int out_size, void* d_ws, size_t ws_size,
                              hipStream_t stream) {
  const float* p_x  = (const float*)d_in[0];
  const int*   p_ei = (const int*)d_in[1];
  const int*   p_bt = (const int*)d_in[2];
  const float* l_x  = (const float*)d_in[3];
  const int*   l_ei = (const int*)d_in[4];
  const int*   l_bt = (const int*)d_in[5];
  const float* pW1 = (const float*)d_in[6],  *pb1 = (const float*)d_in[7];
  const float* pW2 = (const float*)d_in[8],  *pb2 = (const float*)d_in[9];
  const float* pW3 = (const float*)d_in[10], *pb3 = (const float*)d_in[11];
  const float* lW1 = (const float*)d_in[12], *lb1 = (const float*)d_in[13];
  const float* lW2 = (const float*)d_in[14], *lb2 = (const float*)d_in[15];
  const float* lW3 = (const float*)d_in[16], *lb3 = (const float*)d_in[17];
  const float* fc1W = (const float*)d_in[18], *fc1b = (const float*)d_in[19];
  const float* fc2W = (const float*)d_in[20], *fc2b = (const float*)d_in[21];
  const float* oW  = (const float*)d_in[22], *ob  = (const float*)d_in[23];

  const int n_p = in_sizes[2], n_l = in_sizes[5];
  const int E_p = in_sizes[1] / 2, E_l = in_sizes[4] / 2;
  const int IN_P = in_sizes[0] / n_p, IN_L = in_sizes[3] / n_l;   // 41, 78
  const int nr_p = (n_p + 127) & ~127;   // rows padded to 128 for fragment layout

  char* wsc = (char*)d_ws;
  size_t off = 0;
  auto alloc = [&](size_t bytes) -> void* {
    void* p = wsc + off;
    off = (off + bytes + 255) & ~(size_t)255;
    return p;
  };
  float* dinv_p = (float*)alloc((size_t)n_p * 4);
  float* dinv_l = (float*)alloc((size_t)n_l * 4);
  float* cnt_p  = (float*)alloc(512 * 4);
  float* cnt_l  = (float*)alloc(512 * 4);
  float* pooled = (float*)alloc(512 * 512 * 4);
  float* F      = (float*)alloc((size_t)n_p * 128 * 4);
  // AGh+AGl (fragment layout, padded rows); AGf (layer-1 f32 AG) ALIASES the region.
  unsigned short* AGh = (unsigned short*)alloc((size_t)nr_p * 128 * 2);
  unsigned short* AGl = (unsigned short*)alloc((size_t)nr_p * 128 * 2);
  float* AGf    = (float*)AGh;
  unsigned short* W2th = (unsigned short*)alloc(64 * 128 * 2);
  unsigned short* W2tl = (unsigned short*)alloc(64 * 128 * 2);
  unsigned short* W3th = (unsigned short*)alloc(128 * 256 * 2);
  unsigned short* W3tl = (unsigned short*)alloc(128 * 256 * 2);
  int* bsum     = (int*)alloc(1024 * 4);
  int* cur_p    = (int*)alloc((size_t)n_p * 4);
  int* row_p    = (int*)alloc(((size_t)n_p + 1) * 4);
  int* esrc_p   = (int*)alloc((size_t)E_p * 4);
  int* cur_l    = (int*)alloc((size_t)n_l * 4);
  int* row_l    = (int*)alloc(((size_t)n_l + 1) * 4);
  int* esrc_l   = (int*)alloc((size_t)E_l * 4);
  float* fc1o   = F;                 // branches done before the FC stack
  float* fc2o   = F + 512 * 1024;
  (void)ws_size; (void)n_in; (void)out_size;

  hipMemsetAsync(pooled, 0, 512 * 512 * 4, stream);

  auto gemm64 = [&](const float* A, const float* W, const float* b, float* Y,
                    int n, int Kin, int Kout, int ystride) {
    dim3 grd((n + 63) / 64, Kout / 64);
    k_gemm_t<true><<<grd, 256, 0, stream>>>(A, W, b, Y, n, Kin, Kout, ystride);
  };

  auto branch = [&](const float* x0, const int* ei, const int* batch, int n, int E, int IN,
                    const float* W1, const float* b1, const float* W2, const float* b2,
                    const float* W3, const float* b3, float* dinv, float* cnt,
                    int* cursor, int* rowptr, int* esrc, int colbase) {
    const int* src = ei;
    const int* dst = ei + E;
    const int nb = (n + 255) / 256;
    k_fill<<<nb, 256, 0, stream>>>(dinv, 1.0f, n);
    k_deg<<<(E + 255) / 256, 256, 0, stream>>>(dinv, dst, E);
    k_count_sorted<<<2, 256, 0, stream>>>(cnt, batch, n, 512);
    k_scan1<<<nb, 256, 0, stream>>>(dinv, cursor, bsum, n);
    k_scan2<<<1, 1024, 0, stream>>>(bsum, nb);
    k_scan3<<<(n + 256) / 256 + 1, 256, 0, stream>>>(rowptr, cursor, bsum, dinv, n, E);
    k_fill_csr<<<(E + 255) / 256, 256, 0, stream>>>(src, dst, cursor, esrc, E);
    // W pre-split into fragment layout
    k_wsplit<<<(64 * 128 + 255) / 256, 256, 0, stream>>>(W2, W2th, W2tl, 64, 128);
    k_wsplit<<<(128 * 256 + 255) / 256, 256, 0, stream>>>(W3, W3th, W3tl, 128, 256);
    // layer 1 (ragged Kin) -> f32 64-tile
    k_agg<<<(n * 64 + 255) / 256, 256, 0, stream>>>(AGf, x0, rowptr, esrc, dinv, n, IN);
    gemm64(AGf, W1, b1, F, n, IN, 64, 64);
    // layer 2: split agg (16 lanes/node, K=64) -> streaming MFMA GEMM (K=64 -> 128)
    k_agg_split<4><<<(n * 16 + 255) / 256, 256, 0, stream>>>(AGh, AGl, F, rowptr, esrc, dinv, n);
    {
      dim3 grd((n + 127) / 128, 1);
      k_gemm_mfma<64, false><<<grd, 256, 0, stream>>>(AGh, AGl, W2th, W2tl, b2, F,
                                                      n, 128, nullptr, 128, 0);
    }
    // layer 3: split agg (32 lanes/node, K=128) -> streaming MFMA GEMM + fused pool
    k_agg_split<5><<<(n * 32 + 255) / 256, 256, 0, stream>>>(AGh, AGl, F, rowptr, esrc, dinv, n);
    {
      dim3 grd((n + 127) / 128, 2);
      k_gemm_mfma<128, true><<<grd, 256, 0, stream>>>(AGh, AGl, W3th, W3tl, b3, pooled,
                                                      n, 256, batch, 512, colbase);
    }
  };

  branch(p_x, p_ei, p_bt, n_p, E_p, IN_P, pW1, pb1, pW2, pb2, pW3, pb3,
         dinv_p, cnt_p, cur_p, row_p, esrc_p, 0);
  branch(l_x, l_ei, l_bt, n_l, E_l, IN_L, lW1, lb1, lW2, lb2, lW3, lb3,
         dinv_l, cnt_l, cur_l, row_l, esrc_l, 256);

  k_pool_div<<<(512 * 256 + 255) / 256, 256, 0, stream>>>(pooled, cnt_p, 0);
  k_pool_div<<<(512 * 256 + 255) / 256, 256, 0, stream>>>(pooled, cnt_l, 256);

  // FC stack (f32 path)
  gemm64(pooled, fc1W, fc1b, fc1o, 512, 512, 1024, 1024);
  gemm64(fc1o, fc2W, fc2b, fc2o, 512, 1024, 512, 512);
  k_out<<<512, 64, 0, stream>>>((float*)d_out, fc2o, oW, ob);
}

// Round 13
// 1127.480 us; speedup vs baseline: 1.6985x; 1.0639x over previous
//
#include <hip/hip_runtime.h>

typedef __attribute__((ext_vector_type(8))) short short8;
typedef __attribute__((ext_vector_type(16))) float f32x16;

// ---------------- bf16 split helpers ----------------

__device__ __forceinline__ unsigned short f2bf_rne(float f) {
  unsigned u = __float_as_uint(f);
  u += 0x7fffu + ((u >> 16) & 1u);
  return (unsigned short)(u >> 16);
}
__device__ __forceinline__ float bf2f(unsigned short h) {
  return __uint_as_float(((unsigned)h) << 16);
}

// ---------------- small helper kernels ----------------

static __global__ void k_fill(float* __restrict__ p, float v, int n) {
  int i = blockIdx.x * blockDim.x + threadIdx.x;
  if (i < n) p[i] = v;
}

static __global__ void k_deg(float* __restrict__ deg, const int* __restrict__ dst, int E) {
  int e = blockIdx.x * blockDim.x + threadIdx.x;
  if (e < E) atomicAdd(&deg[dst[e]], 1.0f);
}

// cnt[b] = run-length of b in SORTED batch (two binary searches, no atomics)
static __global__ void k_count_sorted(float* __restrict__ cnt, const int* __restrict__ batch,
                                      int n, int nb) {
  int b = blockIdx.x * blockDim.x + threadIdx.x;
  if (b >= nb) return;
  int lo = 0, hi = n;
  while (lo < hi) { int mid = (lo + hi) >> 1; if (batch[mid] < b) lo = mid + 1; else hi = mid; }
  int start = lo;
  lo = 0; hi = n;
  while (lo < hi) { int mid = (lo + hi) >> 1; if (batch[mid] < b + 1) lo = mid + 1; else hi = mid; }
  cnt[b] = (float)(lo - start);
}

// ---------------- CSR build ----------------

static __global__ void k_scan1(const float* __restrict__ degf, int* __restrict__ ex,
                               int* __restrict__ bsum, int n) {
  __shared__ int sm[256];
  int i = blockIdx.x * 256 + threadIdx.x;
  int v = (i < n) ? ((int)degf[i] - 1) : 0;
  sm[threadIdx.x] = v;
  __syncthreads();
  for (int off = 1; off < 256; off <<= 1) {
    int t = (threadIdx.x >= (unsigned)off) ? sm[threadIdx.x - off] : 0;
    __syncthreads();
    sm[threadIdx.x] += t;
    __syncthreads();
  }
  if (i < n) ex[i] = sm[threadIdx.x] - v;
  if (threadIdx.x == 255) bsum[blockIdx.x] = sm[255];
}

static __global__ void k_scan2(int* __restrict__ bsum, int nb) {
  __shared__ int sm[1024];
  __shared__ int carry;
  if (threadIdx.x == 0) carry = 0;
  __syncthreads();
  for (int base = 0; base < nb; base += 1024) {
    int i = base + threadIdx.x;
    int v = (i < nb) ? bsum[i] : 0;
    sm[threadIdx.x] = v;
    __syncthreads();
    for (int off = 1; off < 1024; off <<= 1) {
      int t = (threadIdx.x >= (unsigned)off) ? sm[threadIdx.x - off] : 0;
      __syncthreads();
      sm[threadIdx.x] += t;
      __syncthreads();
    }
    if (i < nb) bsum[i] = sm[threadIdx.x] + carry;
    __syncthreads();
    if (threadIdx.x == 0) carry += sm[1023];
    __syncthreads();
  }
}

static __global__ void k_scan3(int* __restrict__ rowptr, int* __restrict__ cursor_ex,
                               const int* __restrict__ bsum, float* __restrict__ dinv,
                               int n, int E) {
  int i = blockIdx.x * 256 + threadIdx.x;
  if (i > n) return;
  if (i == n) { rowptr[n] = E; return; }
  int add = blockIdx.x ? bsum[blockIdx.x - 1] : 0;
  int r = cursor_ex[i] + add;
  rowptr[i] = r;
  cursor_ex[i] = r;
  dinv[i] = 1.0f / sqrtf(dinv[i]);
}

static __global__ void k_fill_csr(const int* __restrict__ src, const int* __restrict__ dst,
                                  int* __restrict__ cursor, int* __restrict__ esrc, int E) {
  int e = blockIdx.x * 256 + threadIdx.x;
  if (e >= E) return;
  int pos = atomicAdd(&cursor[dst[e]], 1);
  esrc[pos] = src[e];
}

// ---------------- layer-1 pull aggregation (ragged K), 16 lanes/node ----------------
// 4 nodes per wave -> 4 independent edge loops in flight; lane gl owns elements
// {gl, gl+16, ...}: per-group 64B contiguous loads, NE independent loads per edge.
template<int NE>
static __global__ void __launch_bounds__(256)
k_agg16(float* __restrict__ AG, const float* __restrict__ X,
        const int* __restrict__ rowptr, const int* __restrict__ esrc,
        const float* __restrict__ dinv, int n, int K) {
  int gid = (blockIdx.x * blockDim.x + threadIdx.x) >> 4;
  int gl = threadIdx.x & 15;
  if (gid >= n) return;
  int rs = rowptr[gid], re = rowptr[gid + 1];
  float dv = dinv[gid];
  const float* xr = X + (size_t)gid * K;
  float a[NE];
#pragma unroll
  for (int i = 0; i < NE; ++i) {
    int k = gl + i * 16;
    a[i] = (k < K) ? xr[k] * dv * dv : 0.0f;
  }
  for (int e = rs; e < re; ++e) {
    int s = esrc[e];
    float w = dinv[s] * dv;
    const float* xs = X + (size_t)s * K;
#pragma unroll
    for (int i = 0; i < NE; ++i) {
      int k = gl + i * 16;
      if (k < K) a[i] = fmaf(xs[k], w, a[i]);
    }
  }
  float* ar = AG + (size_t)gid * K;
#pragma unroll
  for (int i = 0; i < NE; ++i) {
    int k = gl + i * 16;
    if (k < K) ar[k] = a[i];
  }
}

// ---------------- pull aggregation, split-bf16 out in MFMA-FRAGMENT layout ----------------
// Fragment layout: AG[((rowblk*NCH + chunk)*32 + row&31)*8 + k&7], rowblk=row>>5, chunk=k>>3.
// A wave's GEMM fragment load then reads 1KB fully-contiguous. Group = 2^LG lanes per node.
template<int LG>
static __global__ void __launch_bounds__(256)
k_agg_split(unsigned short* __restrict__ AGh, unsigned short* __restrict__ AGl,
            const float* __restrict__ X,
            const int* __restrict__ rowptr, const int* __restrict__ esrc,
            const float* __restrict__ dinv, int n) {
  const int K = (1 << LG) * 4;
  const int NCH = K / 8;
  int gid = (blockIdx.x * blockDim.x + threadIdx.x) >> LG;   // node id
  int gl = threadIdx.x & ((1 << LG) - 1);                    // lane within group
  if (gid >= n) return;
  int rs = rowptr[gid], re = rowptr[gid + 1];
  float dv = dinv[gid];
  float4 a = *(const float4*)(X + (size_t)gid * K + gl * 4);
  float dv2 = dv * dv;
  a.x *= dv2; a.y *= dv2; a.z *= dv2; a.w *= dv2;
  for (int e = rs; e < re; ++e) {
    int s = esrc[e];
    float w = dinv[s] * dv;
    float4 xs = *(const float4*)(X + (size_t)s * K + gl * 4);
    a.x = fmaf(xs.x, w, a.x);
    a.y = fmaf(xs.y, w, a.y);
    a.z = fmaf(xs.z, w, a.z);
    a.w = fmaf(xs.w, w, a.w);
  }
  int rb = gid >> 5, r = gid & 31;
  int c = gl >> 1;                 // k-chunk (8 elems)
  int half = (gl & 1) * 4;         // which float4 within the chunk
  size_t base = (((size_t)rb * NCH + c) * 32 + r) * 8 + half;
  unsigned short h0 = f2bf_rne(a.x), h1 = f2bf_rne(a.y), h2 = f2bf_rne(a.z), h3 = f2bf_rne(a.w);
  ushort4 hv = {h0, h1, h2, h3};
  ushort4 lv = {f2bf_rne(a.x - bf2f(h0)), f2bf_rne(a.y - bf2f(h1)),
                f2bf_rne(a.z - bf2f(h2)), f2bf_rne(a.w - bf2f(h3))};
  *(ushort4*)&AGh[base] = hv;
  *(ushort4*)&AGl[base] = lv;
}

// ---------------- W pre-split into the same fragment layout (cols play "rows") ----------------
static __global__ void k_wsplit(const float* __restrict__ W,
                                unsigned short* __restrict__ Wth, unsigned short* __restrict__ Wtl,
                                int Kin, int Kout) {
  int idx = blockIdx.x * blockDim.x + threadIdx.x;
  if (idx >= Kin * Kout) return;
  int k = idx / Kout, c = idx - k * Kout;
  float v = W[idx];
  unsigned short h = f2bf_rne(v);
  int cb = c >> 5, c31 = c & 31, ch = k >> 3, k7 = k & 7;
  size_t base = (((size_t)cb * (Kin / 8) + ch) * 32 + c31) * 8 + k7;
  Wth[base] = h;
  Wtl[base] = f2bf_rne(v - bf2f(h));
}

// ---------------- split-bf16 MFMA GEMM: NO LDS, NO BARRIERS ----------------
// Operands pre-arranged in fragment layout; every fragment load is a contiguous
// 1KB wave read (A streams HBM/L3, B is L2-resident weights).
// Block 128x128 (grid.y tiles Kout), 4 waves (2x2), wave 64x64 = 2x2 frags 32x32x16.
// 3-term split: Ah*Bh + Ah*Bl + Al*Bh.
template<int K, bool POOL>
static __global__ void __launch_bounds__(256)
k_gemm_mfma(const unsigned short* __restrict__ Ah, const unsigned short* __restrict__ Al,
            const unsigned short* __restrict__ Bth, const unsigned short* __restrict__ Btl,
            const float* __restrict__ bias, float* __restrict__ Y,
            int n, int Kout,
            const int* __restrict__ batch, int ystride, int colbase) {
  const int NCH = K / 8;
  const int NKK = K / 16;
  const int tid = threadIdx.x;
  const int lane = tid & 63;
  const int wid = tid >> 6;
  const int wr = wid >> 1, wc = wid & 1;
  const int g = lane >> 5;
  const int l31 = lane & 31;
  const int r0 = blockIdx.x * 128;
  const int c0 = blockIdx.y * 128;
  const int rb0 = (r0 >> 5) + wr * 2;   // this wave's two A row-blocks
  const int cb0 = (c0 >> 5) + wc * 2;   // this wave's two B col-blocks

  f32x16 acc[2][2] = {};

#pragma unroll
  for (int kk = 0; kk < NKK; ++kk) {
    const int ch = 2 * kk + g;
    short8 ah[2], al[2], bh[2], bl[2];
#pragma unroll
    for (int f = 0; f < 2; ++f) {
      size_t aoff = (((size_t)(rb0 + f) * NCH + ch) * 32 + l31) * 8;
      ah[f] = *(const short8*)&Ah[aoff];
      al[f] = *(const short8*)&Al[aoff];
      size_t boff = (((size_t)(cb0 + f) * NCH + ch) * 32 + l31) * 8;
      bh[f] = *(const short8*)&Bth[boff];
      bl[f] = *(const short8*)&Btl[boff];
    }
#pragma unroll
    for (int fa = 0; fa < 2; ++fa)
#pragma unroll
      for (int fb = 0; fb < 2; ++fb) {
        acc[fa][fb] = __builtin_amdgcn_mfma_f32_32x32x16_bf16(ah[fa], bh[fb], acc[fa][fb], 0, 0, 0);
        acc[fa][fb] = __builtin_amdgcn_mfma_f32_32x32x16_bf16(ah[fa], bl[fb], acc[fa][fb], 0, 0, 0);
        acc[fa][fb] = __builtin_amdgcn_mfma_f32_32x32x16_bf16(al[fa], bh[fb], acc[fa][fb], 0, 0, 0);
      }
  }

  // epilogue. C/D layout (HW-verified): col = lane&31, row = (reg&3)+8*(reg>>2)+4*(lane>>5)
  if (!POOL) {
#pragma unroll
    for (int fa = 0; fa < 2; ++fa)
#pragma unroll
      for (int fb = 0; fb < 2; ++fb) {
        int col = c0 + wc * 64 + fb * 32 + l31;
        float bcol = bias[col];
#pragma unroll
        for (int r = 0; r < 16; ++r) {
          int grow = r0 + wr * 64 + fa * 32 + (r & 3) + 8 * (r >> 2) + 4 * g;
          if (grow < n) {
            float v = fmaxf(acc[fa][fb][r] + bcol, 0.0f);
            Y[(size_t)grow * ystride + col] = v;
          }
        }
      }
  } else {
#pragma unroll
    for (int fa = 0; fa < 2; ++fa)
#pragma unroll
      for (int fb = 0; fb < 2; ++fb) {
        int col = colbase + c0 + wc * 64 + fb * 32 + l31;
        float bcol = bias[c0 + wc * 64 + fb * 32 + l31];
        float s = 0.0f;
        int cur = -1;
#pragma unroll
        for (int r = 0; r < 16; ++r) {
          int grow = r0 + wr * 64 + fa * 32 + (r & 3) + 8 * (r >> 2) + 4 * g;
          if (grow < n) {
            int b = batch[grow];
            if (b != cur) {
              if (cur >= 0 && s != 0.0f)
                atomicAdd(&Y[(size_t)cur * ystride + col], s);
              cur = b;
              s = 0.0f;
            }
            s += fmaxf(acc[fa][fb][r] + bcol, 0.0f);
          }
        }
        if (cur >= 0 && s != 0.0f)
          atomicAdd(&Y[(size_t)cur * ystride + col], s);
      }
  }
}

// ---------------- 64x64 tiled f32 GEMM (L1 ragged-K + FC stack) ----------------
template<bool RELU>
static __global__ void __launch_bounds__(256)
k_gemm_t(const float* __restrict__ A, const float* __restrict__ W,
         const float* __restrict__ bias, float* __restrict__ Y,
         int n, int Kin, int Kout, int ystride) {
  __shared__ float As[32][68];
  __shared__ float Ws[32][68];

  const int tid = threadIdx.x;
  const int tx = tid & 15, ty = tid >> 4;
  const int r0 = blockIdx.x * 64;
  const int c0 = blockIdx.y * 64;

  float acc[4][4] = {};

  const int ar = tid & 63;
  const int akg = (tid >> 6) * 8;
  const int wkk = tid & 31;
  const int wcg = (tid >> 5) * 8;

  const int nch = (Kin + 31) / 32;
  for (int ch = 0; ch < nch; ++ch) {
    const int k0 = ch * 32;
    {
      int grow = r0 + ar;
      bool rok = grow < n;
      const float* arow = A + (size_t)grow * Kin;
#pragma unroll
      for (int i = 0; i < 8; ++i) {
        int k = k0 + akg + i;
        As[akg + i][ar] = (rok && k < Kin) ? arow[k] : 0.0f;
      }
    }
    {
      int gk = k0 + wkk;
      float4 v0 = make_float4(0.f, 0.f, 0.f, 0.f), v1 = v0;
      if (gk < Kin) {
        const float* wp = W + (size_t)gk * Kout + c0 + wcg;
        v0 = *(const float4*)wp;
        v1 = *(const float4*)(wp + 4);
      }
      *(float4*)&Ws[wkk][wcg] = v0;
      *(float4*)&Ws[wkk][wcg + 4] = v1;
    }
    __syncthreads();
#pragma unroll
    for (int k = 0; k < 32; ++k) {
      float4 a4 = *(const float4*)&As[k][ty * 4];
      float4 w4 = *(const float4*)&Ws[k][tx * 4];
      float av[4] = {a4.x, a4.y, a4.z, a4.w};
      float wv[4] = {w4.x, w4.y, w4.z, w4.w};
#pragma unroll
      for (int i = 0; i < 4; ++i)
#pragma unroll
        for (int j = 0; j < 4; ++j)
          acc[i][j] = fmaf(av[i], wv[j], acc[i][j]);
    }
    __syncthreads();
  }

  float4 bv = *(const float4*)&bias[c0 + tx * 4];
  float bb[4] = {bv.x, bv.y, bv.z, bv.w};
#pragma unroll
  for (int i = 0; i < 4; ++i) {
    int row = r0 + ty * 4 + i;
    if (row < n) {
      float o[4];
#pragma unroll
      for (int j = 0; j < 4; ++j) {
        o[j] = acc[i][j] + bb[j];
        if (RELU) o[j] = fmaxf(o[j], 0.0f);
      }
      *(float4*)&Y[(size_t)row * ystride + c0 + tx * 4] = make_float4(o[0], o[1], o[2], o[3]);
    }
  }
}

// pooled[b, colbase+c] /= max(cnt[b],1)
static __global__ void k_pool_div(float* __restrict__ pooled, const float* __restrict__ cnt,
                                  int colbase) {
  int i = blockIdx.x * blockDim.x + threadIdx.x;
  if (i >= 512 * 256) return;
  int b = i >> 8;
  int c = i & 255;
  pooled[b * 512 + colbase + c] /= fmaxf(cnt[b], 1.0f);
}

// out[row] = X[row,:512] . w + b
static __global__ void k_out(float* __restrict__ out, const float* __restrict__ X,
                             const float* __restrict__ w, const float* __restrict__ b) {
  int row = blockIdx.x;
  int lane = threadIdx.x;
  float acc = 0.f;
  for (int k = lane; k < 512; k += 64)
    acc = fmaf(X[row * 512 + k], w[k], acc);
#pragma unroll
  for (int off = 32; off; off >>= 1) acc += __shfl_down(acc, off);
  if (lane == 0) out[row] = acc + b[0];
}

// ---------------- launch ----------------

extern "C" void kernel_launch(void* const* d_in, const int* in_sizes, int n_in,
                              void* d_out, int out_size, void* d_ws, size_t ws_size,
                              hipStream_t stream) {
  const float* p_x  = (const float*)d_in[0];
  const int*   p_ei = (const int*)d_in[1];
  const int*   p_bt = (const int*)d_in[2];
  const float* l_x  = (const float*)d_in[3];
  const int*   l_ei = (const int*)d_in[4];
  const int*   l_bt = (const int*)d_in[5];
  const float* pW1 = (const float*)d_in[6],  *pb1 = (const float*)d_in[7];
  const float* pW2 = (const float*)d_in[8],  *pb2 = (const float*)d_in[9];
  const float* pW3 = (const float*)d_in[10], *pb3 = (const float*)d_in[11];
  const float* lW1 = (const float*)d_in[12], *lb1 = (const float*)d_in[13];
  const float* lW2 = (const float*)d_in[14], *lb2 = (const float*)d_in[15];
  const float* lW3 = (const float*)d_in[16], *lb3 = (const float*)d_in[17];
  const float* fc1W = (const float*)d_in[18], *fc1b = (const float*)d_in[19];
  const float* fc2W = (const float*)d_in[20], *fc2b = (const float*)d_in[21];
  const float* oW  = (const float*)d_in[22], *ob  = (const float*)d_in[23];

  const int n_p = in_sizes[2], n_l = in_sizes[5];
  const int E_p = in_sizes[1] / 2, E_l = in_sizes[4] / 2;
  const int IN_P = in_sizes[0] / n_p, IN_L = in_sizes[3] / n_l;   // 41, 78
  const int nr_p = (n_p + 127) & ~127;   // rows padded to 128 for fragment layout

  char* wsc = (char*)d_ws;
  size_t off = 0;
  auto alloc = [&](size_t bytes) -> void* {
    void* p = wsc + off;
    off = (off + bytes + 255) & ~(size_t)255;
    return p;
  };
  float* dinv_p = (float*)alloc((size_t)n_p * 4);
  float* dinv_l = (float*)alloc((size_t)n_l * 4);
  float* cnt_p  = (float*)alloc(512 * 4);
  float* cnt_l  = (float*)alloc(512 * 4);
  float* pooled = (float*)alloc(512 * 512 * 4);
  float* F      = (float*)alloc((size_t)n_p * 128 * 4);
  // AGh+AGl (fragment layout, padded rows); AGf (layer-1 f32 AG) ALIASES the region.
  unsigned short* AGh = (unsigned short*)alloc((size_t)nr_p * 128 * 2);
  unsigned short* AGl = (unsigned short*)alloc((size_t)nr_p * 128 * 2);
  float* AGf    = (float*)AGh;
  unsigned short* W2th = (unsigned short*)alloc(64 * 128 * 2);
  unsigned short* W2tl = (unsigned short*)alloc(64 * 128 * 2);
  unsigned short* W3th = (unsigned short*)alloc(128 * 256 * 2);
  unsigned short* W3tl = (unsigned short*)alloc(128 * 256 * 2);
  int* bsum     = (int*)alloc(1024 * 4);
  int* cur_p    = (int*)alloc((size_t)n_p * 4);
  int* row_p    = (int*)alloc(((size_t)n_p + 1) * 4);
  int* esrc_p   = (int*)alloc((size_t)E_p * 4);
  int* cur_l    = (int*)alloc((size_t)n_l * 4);
  int* row_l    = (int*)alloc(((size_t)n_l + 1) * 4);
  int* esrc_l   = (int*)alloc((size_t)E_l * 4);
  float* fc1o   = F;                 // branches done before the FC stack
  float* fc2o   = F + 512 * 1024;
  (void)ws_size; (void)n_in; (void)out_size;

  hipMemsetAsync(pooled, 0, 512 * 512 * 4, stream);

  auto gemm64 = [&](const float* A, const float* W, const float* b, float* Y,
                    int n, int Kin, int Kout, int ystride) {
    dim3 grd((n + 63) / 64, Kout / 64);
    k_gemm_t<true><<<grd, 256, 0, stream>>>(A, W, b, Y, n, Kin, Kout, ystride);
  };

  auto branch = [&](const float* x0, const int* ei, const int* batch, int n, int E, int IN,
                    const float* W1, const float* b1, const float* W2, const float* b2,
                    const float* W3, const float* b3, float* dinv, float* cnt,
                    int* cursor, int* rowptr, int* esrc, int colbase) {
    const int* src = ei;
    const int* dst = ei + E;
    const int nb = (n + 255) / 256;
    k_fill<<<nb, 256, 0, stream>>>(dinv, 1.0f, n);
    k_deg<<<(E + 255) / 256, 256, 0, stream>>>(dinv, dst, E);
    k_count_sorted<<<2, 256, 0, stream>>>(cnt, batch, n, 512);
    k_scan1<<<nb, 256, 0, stream>>>(dinv, cursor, bsum, n);
    k_scan2<<<1, 1024, 0, stream>>>(bsum, nb);
    k_scan3<<<(n + 256) / 256 + 1, 256, 0, stream>>>(rowptr, cursor, bsum, dinv, n, E);
    k_fill_csr<<<(E + 255) / 256, 256, 0, stream>>>(src, dst, cursor, esrc, E);
    // W pre-split into fragment layout
    k_wsplit<<<(64 * 128 + 255) / 256, 256, 0, stream>>>(W2, W2th, W2tl, 64, 128);
    k_wsplit<<<(128 * 256 + 255) / 256, 256, 0, stream>>>(W3, W3th, W3tl, 128, 256);
    // layer 1 (ragged Kin): 16-lane-group agg -> f32 64-tile GEMM
    {
      int gw = (n * 16 + 255) / 256;
      if (IN <= 48)
        k_agg16<3><<<gw, 256, 0, stream>>>(AGf, x0, rowptr, esrc, dinv, n, IN);
      else if (IN <= 80)
        k_agg16<5><<<gw, 256, 0, stream>>>(AGf, x0, rowptr, esrc, dinv, n, IN);
      else
        k_agg16<8><<<gw, 256, 0, stream>>>(AGf, x0, rowptr, esrc, dinv, n, IN);
    }
    gemm64(AGf, W1, b1, F, n, IN, 64, 64);
    // layer 2: split agg (16 lanes/node, K=64) -> streaming MFMA GEMM (K=64 -> 128)
    k_agg_split<4><<<(n * 16 + 255) / 256, 256, 0, stream>>>(AGh, AGl, F, rowptr, esrc, dinv, n);
    {
      dim3 grd((n + 127) / 128, 1);
      k_gemm_mfma<64, false><<<grd, 256, 0, stream>>>(AGh, AGl, W2th, W2tl, b2, F,
                                                      n, 128, nullptr, 128, 0);
    }
    // layer 3: split agg (32 lanes/node, K=128) -> streaming MFMA GEMM + fused pool
    k_agg_split<5><<<(n * 32 + 255) / 256, 256, 0, stream>>>(AGh, AGl, F, rowptr, esrc, dinv, n);
    {
      dim3 grd((n + 127) / 128, 2);
      k_gemm_mfma<128, true><<<grd, 256, 0, stream>>>(AGh, AGl, W3th, W3tl, b3, pooled,
                                                      n, 256, batch, 512, colbase);
    }
  };

  branch(p_x, p_ei, p_bt, n_p, E_p, IN_P, pW1, pb1, pW2, pb2, pW3, pb3,
         dinv_p, cnt_p, cur_p, row_p, esrc_p, 0);
  branch(l_x, l_ei, l_bt, n_l, E_l, IN_L, lW1, lb1, lW2, lb2, lW3, lb3,
         dinv_l, cnt_l, cur_l, row_l, esrc_l, 256);

  k_pool_div<<<(512 * 256 + 255) / 256, 256, 0, stream>>>(pooled, cnt_p, 0);
  k_pool_div<<<(512 * 256 + 255) / 256, 256, 0, stream>>>(pooled, cnt_l, 256);

  // FC stack (f32 path)
  gemm64(pooled, fc1W, fc1b, fc1o, 512, 512, 1024, 1024);
  gemm64(fc1o, fc2W, fc2b, fc2o, 512, 1024, 512, 512);
  k_out<<<512, 64, 0, stream>>>((float*)d_out, fc2o, oW, ob);
}